// Round 1
// baseline (931.334 us; speedup 1.0000x reference)
//
#include <hip/hip_runtime.h>
#include <cmath>

// Problem constants
#define BATCH   64
#define NPG     1024           // nodes per graph
#define NODES   65536          // BATCH*NPG
#define EDGES   524288
#define FIN     14
#define NH      128
#define KP1     820
#define KP2     656

// ---------------------------------------------------------------------------
// conv1 aggregation: agg1[dst] += x[src]   (14-dim, f32 atomics)
// ---------------------------------------------------------------------------
__global__ __launch_bounds__(256) void k_scatter1(
    const float* __restrict__ x, const int* __restrict__ src,
    const int* __restrict__ dst, float* __restrict__ agg1) {
  int e = blockIdx.x * 256 + threadIdx.x;
  if (e >= EDGES) return;
  int s = src[e], d = dst[e];
  const float* xs = x + (size_t)s * FIN;
  float* ad = agg1 + (size_t)d * FIN;
#pragma unroll
  for (int k = 0; k < FIN; ++k) atomicAdd(&ad[k], xs[k]);
}

// ---------------------------------------------------------------------------
// conv1 GEMM + relu + fused pool1 score:
//   h1[n][o] = relu(b1[o] + sum_k W1rel[o][k]*agg1[n][k] + W1root[o][k]*x[n][k])
//   s1[n]    = tanh( (h1[n]·p1w) / ||p1w|| )
// block = 128 threads (one per output feature), 16 nodes per block
// ---------------------------------------------------------------------------
__global__ __launch_bounds__(128) void k_gemm1(
    const float* __restrict__ x, const float* __restrict__ agg1,
    const float* __restrict__ Wrel, const float* __restrict__ brel,
    const float* __restrict__ Wroot, const float* __restrict__ p1w,
    float* __restrict__ h1, float* __restrict__ s1) {
  __shared__ float Wl[128][29];   // pad 28->29: conflict-free stride
  __shared__ float arow[28];
  __shared__ float red[4];
  int t = threadIdx.x;
#pragma unroll
  for (int k = 0; k < FIN; ++k) {
    Wl[t][k]       = Wrel[t * FIN + k];
    Wl[t][FIN + k] = Wroot[t * FIN + k];
  }
  float p1 = p1w[t];
  float b  = brel[t];
  float q  = p1 * p1;
#pragma unroll
  for (int d = 32; d; d >>= 1) q += __shfl_xor(q, d);
  if ((t & 63) == 0) red[t >> 6] = q;
  __syncthreads();
  float rnorm = rsqrtf(red[0] + red[1]);

  int n0 = blockIdx.x * 16;
  for (int i = 0; i < 16; ++i) {
    int n = n0 + i;
    __syncthreads();               // protect arow/red from previous iteration
    if (t < FIN)            arow[t] = agg1[(size_t)n * FIN + t];
    else if (t < 2 * FIN)   arow[t] = x[(size_t)n * FIN + (t - FIN)];
    __syncthreads();
    float acc = b;
#pragma unroll
    for (int k = 0; k < 2 * FIN; ++k) acc += Wl[t][k] * arow[k];
    acc = fmaxf(acc, 0.f);
    h1[(size_t)n * NH + t] = acc;
    float pp = acc * p1;
#pragma unroll
    for (int d = 32; d; d >>= 1) pp += __shfl_xor(pp, d);
    if ((t & 63) == 0) red[2 + (t >> 6)] = pp;
    __syncthreads();
    if (t == 0) s1[n] = tanhf((red[2] + red[3]) * rnorm);
  }
}

// ---------------------------------------------------------------------------
// exact per-graph top-K via bitonic sort of 1024 (score,idx) keys.
// mask_in (optional): nodes with mask_in==0 get -inf keys (excluded).
// kept[n] = 1 for the K best nodes of each graph, else 0 (fully written).
// ---------------------------------------------------------------------------
__global__ __launch_bounds__(1024) void k_topk(
    const float* __restrict__ score, const int* __restrict__ mask_in,
    int* __restrict__ kept, int K) {
  __shared__ unsigned long long keys[1024];
  int t = threadIdx.x;
  int g = blockIdx.x;
  int n = g * NPG + t;
  unsigned int inv;
  if (mask_in && !mask_in[n]) {
    inv = 0xFFFFFFFFu;                       // sorts last (lowest score)
  } else {
    unsigned int u   = __float_as_uint(score[n]);
    unsigned int ord = (u & 0x80000000u) ? ~u : (u | 0x80000000u);
    inv = ~ord;                              // ascending inv == descending score
  }
  keys[t] = ((unsigned long long)inv << 32) | (unsigned int)t;
  __syncthreads();
  for (int k = 2; k <= 1024; k <<= 1) {
    for (int j = k >> 1; j > 0; j >>= 1) {
      int ixj = t ^ j;
      if (ixj > t) {
        unsigned long long a = keys[t], b = keys[ixj];
        bool up = ((t & k) == 0);
        if ((a > b) == up) { keys[t] = b; keys[ixj] = a; }
      }
      __syncthreads();
    }
  }
  int idx = (int)(keys[t] & 0xFFFFFFFFu);
  kept[g * NPG + idx] = (t < K) ? 1 : 0;
}

// ---------------------------------------------------------------------------
// pool1 apply + readout1 partials:
//   sx[n] = kept1[n] ? h1[n]*s1[n] : 0   (in place over h1)
//   partial sum/max per (graph, chunk-of-256-nodes, feature)
// grid = 64*4 blocks, 128 threads (one per feature)
// ---------------------------------------------------------------------------
__global__ __launch_bounds__(128) void k_sx_readout1(
    float* __restrict__ h1, const float* __restrict__ s1,
    const int* __restrict__ kept1, float* __restrict__ psum,
    float* __restrict__ pmax) {
  int g = blockIdx.x >> 2, c = blockIdx.x & 3;
  int f = threadIdx.x;
  int nbase = g * NPG + c * 256;
  float sum = 0.f, mx = -1e30f;
  for (int i = 0; i < 256; ++i) {
    int n = nbase + i;
    float v = 0.f;
    if (kept1[n]) {
      v = h1[(size_t)n * NH + f] * s1[n];
      sum += v;
      mx = fmaxf(mx, v);
    }
    h1[(size_t)n * NH + f] = v;   // becomes sx
  }
  psum[(size_t)blockIdx.x * NH + f] = sum;
  pmax[(size_t)blockIdx.x * NH + f] = mx;
}

// ---------------------------------------------------------------------------
// conv2 aggregation: agg2[dst] += sx[src] for edges with both endpoints kept.
// one wave per edge; lane handles 2 consecutive features (float2 read).
// ---------------------------------------------------------------------------
__global__ __launch_bounds__(256) void k_scatter2(
    const float* __restrict__ sx, const int* __restrict__ src,
    const int* __restrict__ dst, const int* __restrict__ kept1,
    float* __restrict__ agg2) {
  int e = blockIdx.x * 4 + (threadIdx.x >> 6);
  int lane = threadIdx.x & 63;
  int s = src[e], d = dst[e];
  if (!kept1[s] || !kept1[d]) return;
  float2 v = *(const float2*)(sx + (size_t)s * NH + lane * 2);
  float* arow = agg2 + (size_t)d * NH + lane * 2;
  atomicAdd(&arow[0], v.x);
  atomicAdd(&arow[1], v.y);
}

// ---------------------------------------------------------------------------
// prep for gemm2: Wt[k][o] = k<128 ? W2rel[o][k] : W2root[o][k-128]
// ---------------------------------------------------------------------------
__global__ __launch_bounds__(256) void k_prep_wt2(
    const float* __restrict__ Wrel, const float* __restrict__ Wroot,
    float* __restrict__ Wt) {
  int id = blockIdx.x * 256 + threadIdx.x;   // 32768 total
  int k = id >> 7, o = id & 127;
  Wt[id] = (k < NH) ? Wrel[o * NH + k] : Wroot[o * NH + (k - NH)];
}

__global__ __launch_bounds__(128) void k_prep_norm2(
    const float* __restrict__ p2w, float* __restrict__ rnorm2) {
  __shared__ float red[2];
  int t = threadIdx.x;
  float q = p2w[t] * p2w[t];
#pragma unroll
  for (int d = 32; d; d >>= 1) q += __shfl_xor(q, d);
  if ((t & 63) == 0) red[t >> 6] = q;
  __syncthreads();
  if (t == 0) *rnorm2 = rsqrtf(red[0] + red[1]);
}

// ---------------------------------------------------------------------------
// conv2 GEMM (K=256 concat of [agg2|sx]) + bias + relu + fused pool2 score.
// block = 256 threads computes 64 nodes x 128 outs; thread = 4 nodes x 8 outs.
// ---------------------------------------------------------------------------
__global__ __launch_bounds__(256) void k_gemm2(
    const float* __restrict__ agg2, const float* __restrict__ sx,
    const float* __restrict__ Wt, const float* __restrict__ b2,
    const float* __restrict__ p2w, const float* __restrict__ rnorm2p,
    float* __restrict__ h2, float* __restrict__ s2) {
  __shared__ float Al[64][17];          // A tile, padded
  __shared__ float Wl[16 * 128];        // W tile
  int t  = threadIdx.x;
  int nb = blockIdx.x * 64;
  int og = t & 15;                       // out group: outs og*8 .. og*8+7
  int ng = t >> 4;                       // node group: nodes ng*4 .. ng*4+3
  float acc[4][8];
#pragma unroll
  for (int i = 0; i < 4; ++i)
#pragma unroll
    for (int j = 0; j < 8; ++j) acc[i][j] = 0.f;

  int lrow = t >> 2, lcol = (t & 3) * 4;
  for (int kc = 0; kc < 16; ++kc) {
    __syncthreads();
    const float* srcA = (kc < 8) ? agg2 : sx;
    int kbase = (kc < 8) ? kc * 16 : (kc - 8) * 16;
    float4 av = *(const float4*)(srcA + (size_t)(nb + lrow) * NH + kbase + lcol);
    Al[lrow][lcol + 0] = av.x;
    Al[lrow][lcol + 1] = av.y;
    Al[lrow][lcol + 2] = av.z;
    Al[lrow][lcol + 3] = av.w;
    float4 w0 = *(const float4*)(Wt + kc * 2048 + t * 8);
    float4 w1 = *(const float4*)(Wt + kc * 2048 + t * 8 + 4);
    *(float4*)&Wl[t * 8]     = w0;
    *(float4*)&Wl[t * 8 + 4] = w1;
    __syncthreads();
#pragma unroll
    for (int kk = 0; kk < 16; ++kk) {
      float a0 = Al[ng * 4 + 0][kk];
      float a1 = Al[ng * 4 + 1][kk];
      float a2 = Al[ng * 4 + 2][kk];
      float a3 = Al[ng * 4 + 3][kk];
      const float* wr = &Wl[kk * 128 + og * 8];
      float w[8];
#pragma unroll
      for (int j = 0; j < 8; ++j) w[j] = wr[j];
#pragma unroll
      for (int j = 0; j < 8; ++j) {
        acc[0][j] += a0 * w[j];
        acc[1][j] += a1 * w[j];
        acc[2][j] += a2 * w[j];
        acc[3][j] += a3 * w[j];
      }
    }
  }

  float rnorm = *rnorm2p;
  float bb[8], pw[8];
#pragma unroll
  for (int j = 0; j < 8; ++j) {
    bb[j] = b2[og * 8 + j];
    pw[j] = p2w[og * 8 + j];
  }
#pragma unroll
  for (int i = 0; i < 4; ++i) {
    int n = nb + ng * 4 + i;
    float pv = 0.f;
#pragma unroll
    for (int j = 0; j < 8; ++j) {
      float v = fmaxf(acc[i][j] + bb[j], 0.f);
      acc[i][j] = v;
      pv += v * pw[j];
    }
    *(float4*)(h2 + (size_t)n * NH + og * 8) =
        make_float4(acc[i][0], acc[i][1], acc[i][2], acc[i][3]);
    *(float4*)(h2 + (size_t)n * NH + og * 8 + 4) =
        make_float4(acc[i][4], acc[i][5], acc[i][6], acc[i][7]);
    // reduce pv across the 16 lanes holding this node's 128 outs
    pv += __shfl_xor(pv, 1);
    pv += __shfl_xor(pv, 2);
    pv += __shfl_xor(pv, 4);
    pv += __shfl_xor(pv, 8);
    if (og == 0) s2[n] = tanhf(pv * rnorm);
  }
}

// ---------------------------------------------------------------------------
// readout2 partials over kept2 nodes: v = h2[n]*s2[n]
// ---------------------------------------------------------------------------
__global__ __launch_bounds__(128) void k_readout2(
    const float* __restrict__ h2, const float* __restrict__ s2,
    const int* __restrict__ kept2, float* __restrict__ psum,
    float* __restrict__ pmax) {
  int g = blockIdx.x >> 2, c = blockIdx.x & 3;
  int f = threadIdx.x;
  int nbase = g * NPG + c * 256;
  float sum = 0.f, mx = -1e30f;
  for (int i = 0; i < 256; ++i) {
    int n = nbase + i;
    if (kept2[n]) {
      float v = h2[(size_t)n * NH + f] * s2[n];
      sum += v;
      mx = fmaxf(mx, v);
    }
  }
  psum[(size_t)blockIdx.x * NH + f] = sum;
  pmax[(size_t)blockIdx.x * NH + f] = mx;
}

// ---------------------------------------------------------------------------
// final: out[g][f] = mean1+mean2 (f<128) ; max1+max2 (f>=128)
// ---------------------------------------------------------------------------
__global__ __launch_bounds__(256) void k_final(
    const float* __restrict__ psum1, const float* __restrict__ pmax1,
    const float* __restrict__ psum2, const float* __restrict__ pmax2,
    float* __restrict__ out) {
  int g = blockIdx.x, t = threadIdx.x;
  if (t < 128) {
    float a = 0.f, b = 0.f;
#pragma unroll
    for (int c = 0; c < 4; ++c) {
      a += psum1[(size_t)(g * 4 + c) * NH + t];
      b += psum2[(size_t)(g * 4 + c) * NH + t];
    }
    out[(size_t)g * 256 + t] = a / (float)KP1 + b / (float)KP2;
  } else {
    int f = t - 128;
    float a = -1e30f, b = -1e30f;
#pragma unroll
    for (int c = 0; c < 4; ++c) {
      a = fmaxf(a, pmax1[(size_t)(g * 4 + c) * NH + f]);
      b = fmaxf(b, pmax2[(size_t)(g * 4 + c) * NH + f]);
    }
    out[(size_t)g * 256 + t] = a + b;
  }
}

// ---------------------------------------------------------------------------
extern "C" void kernel_launch(void* const* d_in, const int* in_sizes, int n_in,
                              void* d_out, int out_size, void* d_ws, size_t ws_size,
                              hipStream_t stream) {
  const float* x     = (const float*)d_in[0];
  const int*   eidx  = (const int*)d_in[1];
  const int*   src   = eidx;
  const int*   dst   = eidx + EDGES;
  // d_in[2] = batch (unused; graphs are fixed-size)
  const float* W1rel = (const float*)d_in[3];
  const float* b1    = (const float*)d_in[4];
  const float* W1rt  = (const float*)d_in[5];
  const float* p1w   = (const float*)d_in[6];
  const float* W2rel = (const float*)d_in[7];
  const float* b2    = (const float*)d_in[8];
  const float* W2rt  = (const float*)d_in[9];
  const float* p2w   = (const float*)d_in[10];
  float* out = (float*)d_out;

  // workspace layout (floats)
  float* ws = (float*)d_ws;
  size_t off = 0;
  float* h1    = ws + off; off += (size_t)NODES * NH;      // h1, then sx in place
  float* agg2  = ws + off; off += (size_t)NODES * NH;
  float* h2    = ws + off; off += (size_t)NODES * NH;
  float* agg1  = ws + off; off += (size_t)NODES * FIN;
  float* s1    = ws + off; off += NODES;
  float* s2    = ws + off; off += NODES;
  int*   kept1 = (int*)(ws + off); off += NODES;
  int*   kept2 = (int*)(ws + off); off += NODES;
  float* psum1 = ws + off; off += 256 * NH;
  float* pmax1 = ws + off; off += 256 * NH;
  float* psum2 = ws + off; off += 256 * NH;
  float* pmax2 = ws + off; off += 256 * NH;
  float* Wt2   = ws + off; off += 256 * NH;
  float* rn2   = ws + off; off += 1;

  hipMemsetAsync(agg1, 0, (size_t)NODES * FIN * sizeof(float), stream);
  hipMemsetAsync(agg2, 0, (size_t)NODES * NH * sizeof(float), stream);

  k_scatter1<<<EDGES / 256, 256, 0, stream>>>(x, src, dst, agg1);
  k_gemm1<<<NODES / 16, 128, 0, stream>>>(x, agg1, W1rel, b1, W1rt, p1w, h1, s1);
  k_topk<<<BATCH, 1024, 0, stream>>>(s1, nullptr, kept1, KP1);
  k_sx_readout1<<<BATCH * 4, 128, 0, stream>>>(h1, s1, kept1, psum1, pmax1);
  k_scatter2<<<EDGES / 4, 256, 0, stream>>>(h1, src, dst, kept1, agg2);
  k_prep_wt2<<<128, 256, 0, stream>>>(W2rel, W2rt, Wt2);
  k_prep_norm2<<<1, 128, 0, stream>>>(p2w, rn2);
  k_gemm2<<<NODES / 64, 256, 0, stream>>>(agg2, h1, Wt2, b2, p2w, rn2, h2, s2);
  k_topk<<<BATCH, 1024, 0, stream>>>(s2, kept1, kept2, KP2);
  k_readout2<<<BATCH * 4, 128, 0, stream>>>(h2, s2, kept2, psum2, pmax2);
  k_final<<<BATCH, 256, 0, stream>>>(psum1, pmax1, psum2, pmax2, out);
}

// Round 2
// 536.247 us; speedup vs baseline: 1.7368x; 1.7368x over previous
//
#include <hip/hip_runtime.h>
#include <cmath>

// Problem constants
#define BATCH   64
#define NPG     1024           // nodes per graph
#define NODES   65536          // BATCH*NPG
#define EDGES   524288
#define FIN     14
#define NH      128
#define KP1     820
#define KP2     656

// ---------------------------------------------------------------------------
// CSR build (by dst): histogram -> 2-level exclusive scan -> fill
// ---------------------------------------------------------------------------
__global__ __launch_bounds__(256) void k_hist(
    const int* __restrict__ dst, int* __restrict__ cnt) {
  int e = blockIdx.x * 256 + threadIdx.x;
  atomicAdd(&cnt[dst[e]], 1);
}

__global__ __launch_bounds__(256) void k_scan_local(
    const int* __restrict__ cnt, int* __restrict__ rowptr,
    int* __restrict__ bsum) {
  __shared__ int s[256];
  int t = threadIdx.x, b = blockIdx.x;
  int v = cnt[b * 256 + t];
  s[t] = v;
  __syncthreads();
  for (int d = 1; d < 256; d <<= 1) {
    int add = (t >= d) ? s[t - d] : 0;
    __syncthreads();
    s[t] += add;
    __syncthreads();
  }
  rowptr[b * 256 + t] = s[t] - v;      // exclusive, block-local
  if (t == 255) bsum[b] = s[255];
}

__global__ __launch_bounds__(256) void k_scan_base(
    const int* __restrict__ bsum, int* __restrict__ bbase) {
  __shared__ int s[256];
  int t = threadIdx.x;
  int v = bsum[t];
  s[t] = v;
  __syncthreads();
  for (int d = 1; d < 256; d <<= 1) {
    int add = (t >= d) ? s[t - d] : 0;
    __syncthreads();
    s[t] += add;
    __syncthreads();
  }
  bbase[t] = s[t] - v;                 // exclusive
}

__global__ __launch_bounds__(256) void k_scan_final(
    int* __restrict__ rowptr, const int* __restrict__ bbase,
    int* __restrict__ cursor) {
  int id = blockIdx.x * 256 + threadIdx.x;
  int v = rowptr[id] + bbase[blockIdx.x];
  rowptr[id] = v;
  cursor[id] = v;
  if (id == 0) rowptr[NODES] = EDGES;
}

__global__ __launch_bounds__(256) void k_fill(
    const int* __restrict__ src, const int* __restrict__ dst,
    int* __restrict__ cursor, int* __restrict__ col) {
  int e = blockIdx.x * 256 + threadIdx.x;
  int pos = atomicAdd(&cursor[dst[e]], 1);
  col[pos] = src[e];
}

// ---------------------------------------------------------------------------
// conv1 aggregation via CSR gather: agg1[n] = sum over incoming edges x[src]
// 16 lanes per node (14 active), x is L2-resident (3.6 MB)
// ---------------------------------------------------------------------------
__global__ __launch_bounds__(256) void k_gather1(
    const float* __restrict__ x, const int* __restrict__ rowptr,
    const int* __restrict__ col, float* __restrict__ agg1) {
  int t = threadIdx.x;
  int gi = t >> 4, l = t & 15;
  int n = blockIdx.x * 16 + gi;
  int rs = rowptr[n], re = rowptr[n + 1];
  if (l < FIN) {
    float acc = 0.f;
    for (int j = rs; j < re; ++j) {
      int v = col[j];
      acc += x[(size_t)v * FIN + l];
    }
    agg1[(size_t)n * FIN + l] = acc;
  }
}

// ---------------------------------------------------------------------------
// conv1 GEMM + relu + fused pool1 score (unchanged from round 1)
// ---------------------------------------------------------------------------
__global__ __launch_bounds__(128) void k_gemm1(
    const float* __restrict__ x, const float* __restrict__ agg1,
    const float* __restrict__ Wrel, const float* __restrict__ brel,
    const float* __restrict__ Wroot, const float* __restrict__ p1w,
    float* __restrict__ h1, float* __restrict__ s1) {
  __shared__ float Wl[128][29];
  __shared__ float arow[28];
  __shared__ float red[4];
  int t = threadIdx.x;
#pragma unroll
  for (int k = 0; k < FIN; ++k) {
    Wl[t][k]       = Wrel[t * FIN + k];
    Wl[t][FIN + k] = Wroot[t * FIN + k];
  }
  float p1 = p1w[t];
  float b  = brel[t];
  float q  = p1 * p1;
#pragma unroll
  for (int d = 32; d; d >>= 1) q += __shfl_xor(q, d);
  if ((t & 63) == 0) red[t >> 6] = q;
  __syncthreads();
  float rnorm = rsqrtf(red[0] + red[1]);

  int n0 = blockIdx.x * 16;
  for (int i = 0; i < 16; ++i) {
    int n = n0 + i;
    __syncthreads();
    if (t < FIN)            arow[t] = agg1[(size_t)n * FIN + t];
    else if (t < 2 * FIN)   arow[t] = x[(size_t)n * FIN + (t - FIN)];
    __syncthreads();
    float acc = b;
#pragma unroll
    for (int k = 0; k < 2 * FIN; ++k) acc += Wl[t][k] * arow[k];
    acc = fmaxf(acc, 0.f);
    h1[(size_t)n * NH + t] = acc;
    float pp = acc * p1;
#pragma unroll
    for (int d = 32; d; d >>= 1) pp += __shfl_xor(pp, d);
    if ((t & 63) == 0) red[2 + (t >> 6)] = pp;
    __syncthreads();
    if (t == 0) s1[n] = tanhf((red[2] + red[3]) * rnorm);
  }
}

// ---------------------------------------------------------------------------
// exact per-graph top-K via bitonic sort (unchanged)
// ---------------------------------------------------------------------------
__global__ __launch_bounds__(1024) void k_topk(
    const float* __restrict__ score, const int* __restrict__ mask_in,
    int* __restrict__ kept, int K) {
  __shared__ unsigned long long keys[1024];
  int t = threadIdx.x;
  int g = blockIdx.x;
  int n = g * NPG + t;
  unsigned int inv;
  if (mask_in && !mask_in[n]) {
    inv = 0xFFFFFFFFu;
  } else {
    unsigned int u   = __float_as_uint(score[n]);
    unsigned int ord = (u & 0x80000000u) ? ~u : (u | 0x80000000u);
    inv = ~ord;
  }
  keys[t] = ((unsigned long long)inv << 32) | (unsigned int)t;
  __syncthreads();
  for (int k = 2; k <= 1024; k <<= 1) {
    for (int j = k >> 1; j > 0; j >>= 1) {
      int ixj = t ^ j;
      if (ixj > t) {
        unsigned long long a = keys[t], b = keys[ixj];
        bool up = ((t & k) == 0);
        if ((a > b) == up) { keys[t] = b; keys[ixj] = a; }
      }
      __syncthreads();
    }
  }
  int idx = (int)(keys[t] & 0xFFFFFFFFu);
  kept[g * NPG + idx] = (t < K) ? 1 : 0;
}

// ---------------------------------------------------------------------------
// pool1 apply + readout1 partials (8 chunks of 128 nodes per graph)
// ---------------------------------------------------------------------------
__global__ __launch_bounds__(128) void k_sx_readout1(
    float* __restrict__ h1, const float* __restrict__ s1,
    const int* __restrict__ kept1, float* __restrict__ psum,
    float* __restrict__ pmax) {
  int g = blockIdx.x >> 3, c = blockIdx.x & 7;
  int f = threadIdx.x;
  int nbase = g * NPG + c * 128;
  float sum = 0.f, mx = -1e30f;
  for (int i = 0; i < 128; ++i) {
    int n = nbase + i;
    float v = 0.f;
    if (kept1[n]) {
      v = h1[(size_t)n * NH + f] * s1[n];
      sum += v;
      mx = fmaxf(mx, v);
    }
    h1[(size_t)n * NH + f] = v;   // becomes sx
  }
  psum[(size_t)blockIdx.x * NH + f] = sum;
  pmax[(size_t)blockIdx.x * NH + f] = mx;
}

// ---------------------------------------------------------------------------
// prep for conv2 GEMM: Wt[k][o] = k<128 ? W2rel[o][k] : W2root[o][k-128]
// ---------------------------------------------------------------------------
__global__ __launch_bounds__(256) void k_prep_wt2(
    const float* __restrict__ Wrel, const float* __restrict__ Wroot,
    float* __restrict__ Wt) {
  int id = blockIdx.x * 256 + threadIdx.x;
  int k = id >> 7, o = id & 127;
  Wt[id] = (k < NH) ? Wrel[o * NH + k] : Wroot[o * NH + (k - NH)];
}

__global__ __launch_bounds__(128) void k_prep_norm2(
    const float* __restrict__ p2w, float* __restrict__ rnorm2) {
  __shared__ float red[2];
  int t = threadIdx.x;
  float q = p2w[t] * p2w[t];
#pragma unroll
  for (int d = 32; d; d >>= 1) q += __shfl_xor(q, d);
  if ((t & 63) == 0) red[t >> 6] = q;
  __syncthreads();
  if (t == 0) *rnorm2 = rsqrtf(red[0] + red[1]);
}

// ---------------------------------------------------------------------------
// FUSED conv2: CSR-gather agg tile into LDS + GEMM(K=256) + relu + score.
// Block = 256 threads, 64 dst nodes. No atomics, no agg2 round-trip.
// sx rows of dropped nodes are zero => edge masking by src is implicit;
// dropped dst rows are zeroed (their h2/s2 are masked out by topk2).
// ---------------------------------------------------------------------------
__global__ __launch_bounds__(256) void k_conv2(
    const float* __restrict__ sx, const int* __restrict__ rowptr,
    const int* __restrict__ col, const int* __restrict__ kept1,
    const float* __restrict__ Wt, const float* __restrict__ b2,
    const float* __restrict__ p2w, const float* __restrict__ rnorm2p,
    float* __restrict__ h2, float* __restrict__ s2) {
  __shared__ float Als[64][130];   // gathered agg tile (K 0..127), pad->bank-free
  __shared__ float Al[64][17];     // per-kc staging for sx half (K 128..255)
  __shared__ float Wl[16 * 128];
  int t = threadIdx.x;
  int nb = blockIdx.x * 64;
  int wave = t >> 6, lane = t & 63;

  // ---- gather phase: each wave gathers 16 dst rows (128 f32 each) ----
  for (int i = 0; i < 16; ++i) {
    int nl = wave * 16 + i;
    int d = nb + nl;
    float ax = 0.f, ay = 0.f;
    if (kept1[d]) {
      int rs = rowptr[d], re = rowptr[d + 1];
      for (int j = rs; j < re; ++j) {
        int v = col[j];
        float2 sv = *(const float2*)(sx + (size_t)v * NH + lane * 2);
        ax += sv.x; ay += sv.y;
      }
    }
    *(float2*)&Als[nl][lane * 2] = make_float2(ax, ay);
  }

  // ---- GEMM phase ----
  int og = t & 15;                  // outs o = og + 16*j handled via blocks of 8
  int ng = t >> 4;                  // nodes ng*4 .. ng*4+3
  float acc[4][8];
#pragma unroll
  for (int i = 0; i < 4; ++i)
#pragma unroll
    for (int j = 0; j < 8; ++j) acc[i][j] = 0.f;

  int lrow = t >> 2, lcol = (t & 3) * 4;
  for (int kc = 0; kc < 16; ++kc) {
    __syncthreads();
    if (kc >= 8) {
      int kbase = (kc - 8) * 16;
      float4 av = *(const float4*)(sx + (size_t)(nb + lrow) * NH + kbase + lcol);
      Al[lrow][lcol + 0] = av.x;
      Al[lrow][lcol + 1] = av.y;
      Al[lrow][lcol + 2] = av.z;
      Al[lrow][lcol + 3] = av.w;
    }
    float4 w0 = *(const float4*)(Wt + kc * 2048 + t * 8);
    float4 w1 = *(const float4*)(Wt + kc * 2048 + t * 8 + 4);
    *(float4*)&Wl[t * 8]     = w0;
    *(float4*)&Wl[t * 8 + 4] = w1;
    __syncthreads();
#pragma unroll
    for (int kk = 0; kk < 16; ++kk) {
      float a0, a1, a2, a3;
      if (kc < 8) {
        int c = kc * 16 + kk;
        a0 = Als[ng * 4 + 0][c];
        a1 = Als[ng * 4 + 1][c];
        a2 = Als[ng * 4 + 2][c];
        a3 = Als[ng * 4 + 3][c];
      } else {
        a0 = Al[ng * 4 + 0][kk];
        a1 = Al[ng * 4 + 1][kk];
        a2 = Al[ng * 4 + 2][kk];
        a3 = Al[ng * 4 + 3][kk];
      }
      const float* wr = &Wl[kk * 128 + og * 8];
      float w[8];
#pragma unroll
      for (int j = 0; j < 8; ++j) w[j] = wr[j];
#pragma unroll
      for (int j = 0; j < 8; ++j) {
        acc[0][j] += a0 * w[j];
        acc[1][j] += a1 * w[j];
        acc[2][j] += a2 * w[j];
        acc[3][j] += a3 * w[j];
      }
    }
  }

  float rnorm = *rnorm2p;
  float bb[8], pw[8];
#pragma unroll
  for (int j = 0; j < 8; ++j) {
    bb[j] = b2[og * 8 + j];
    pw[j] = p2w[og * 8 + j];
  }
#pragma unroll
  for (int i = 0; i < 4; ++i) {
    int n = nb + ng * 4 + i;
    float pv = 0.f;
#pragma unroll
    for (int j = 0; j < 8; ++j) {
      float v = fmaxf(acc[i][j] + bb[j], 0.f);
      acc[i][j] = v;
      pv += v * pw[j];
    }
    *(float4*)(h2 + (size_t)n * NH + og * 8) =
        make_float4(acc[i][0], acc[i][1], acc[i][2], acc[i][3]);
    *(float4*)(h2 + (size_t)n * NH + og * 8 + 4) =
        make_float4(acc[i][4], acc[i][5], acc[i][6], acc[i][7]);
    pv += __shfl_xor(pv, 1);
    pv += __shfl_xor(pv, 2);
    pv += __shfl_xor(pv, 4);
    pv += __shfl_xor(pv, 8);
    if (og == 0) s2[n] = tanhf(pv * rnorm);
  }
}

// ---------------------------------------------------------------------------
// readout2 partials over kept2 nodes (8 chunks of 128 nodes per graph)
// ---------------------------------------------------------------------------
__global__ __launch_bounds__(128) void k_readout2(
    const float* __restrict__ h2, const float* __restrict__ s2,
    const int* __restrict__ kept2, float* __restrict__ psum,
    float* __restrict__ pmax) {
  int g = blockIdx.x >> 3, c = blockIdx.x & 7;
  int f = threadIdx.x;
  int nbase = g * NPG + c * 128;
  float sum = 0.f, mx = -1e30f;
  for (int i = 0; i < 128; ++i) {
    int n = nbase + i;
    if (kept2[n]) {
      float v = h2[(size_t)n * NH + f] * s2[n];
      sum += v;
      mx = fmaxf(mx, v);
    }
  }
  psum[(size_t)blockIdx.x * NH + f] = sum;
  pmax[(size_t)blockIdx.x * NH + f] = mx;
}

// ---------------------------------------------------------------------------
// final combine (8 chunks per graph)
// ---------------------------------------------------------------------------
__global__ __launch_bounds__(256) void k_final(
    const float* __restrict__ psum1, const float* __restrict__ pmax1,
    const float* __restrict__ psum2, const float* __restrict__ pmax2,
    float* __restrict__ out) {
  int g = blockIdx.x, t = threadIdx.x;
  if (t < 128) {
    float a = 0.f, b = 0.f;
#pragma unroll
    for (int c = 0; c < 8; ++c) {
      a += psum1[(size_t)(g * 8 + c) * NH + t];
      b += psum2[(size_t)(g * 8 + c) * NH + t];
    }
    out[(size_t)g * 256 + t] = a / (float)KP1 + b / (float)KP2;
  } else {
    int f = t - 128;
    float a = -1e30f, b = -1e30f;
#pragma unroll
    for (int c = 0; c < 8; ++c) {
      a = fmaxf(a, pmax1[(size_t)(g * 8 + c) * NH + f]);
      b = fmaxf(b, pmax2[(size_t)(g * 8 + c) * NH + f]);
    }
    out[(size_t)g * 256 + t] = a + b;
  }
}

// ---------------------------------------------------------------------------
extern "C" void kernel_launch(void* const* d_in, const int* in_sizes, int n_in,
                              void* d_out, int out_size, void* d_ws, size_t ws_size,
                              hipStream_t stream) {
  const float* x     = (const float*)d_in[0];
  const int*   eidx  = (const int*)d_in[1];
  const int*   src   = eidx;
  const int*   dst   = eidx + EDGES;
  const float* W1rel = (const float*)d_in[3];
  const float* b1    = (const float*)d_in[4];
  const float* W1rt  = (const float*)d_in[5];
  const float* p1w   = (const float*)d_in[6];
  const float* W2rel = (const float*)d_in[7];
  const float* b2    = (const float*)d_in[8];
  const float* W2rt  = (const float*)d_in[9];
  const float* p2w   = (const float*)d_in[10];
  float* out = (float*)d_out;

  // workspace layout (floats)
  float* ws = (float*)d_ws;
  size_t off = 0;
  float* h1    = ws + off; off += (size_t)NODES * NH;   // h1, then sx in place
  float* h2    = ws + off; off += (size_t)NODES * NH;
  float* agg1  = ws + off; off += (size_t)NODES * FIN;
  float* s1    = ws + off; off += NODES;
  float* s2    = ws + off; off += NODES;
  int*   kept1 = (int*)(ws + off); off += NODES;
  int*   kept2 = (int*)(ws + off); off += NODES;
  float* psum1 = ws + off; off += 512 * NH;
  float* pmax1 = ws + off; off += 512 * NH;
  float* psum2 = ws + off; off += 512 * NH;
  float* pmax2 = ws + off; off += 512 * NH;
  float* Wt2   = ws + off; off += 256 * NH;
  float* rn2   = ws + off; off += 1;
  int*   cnt     = (int*)(ws + off); off += NODES;
  int*   rowptr  = (int*)(ws + off); off += NODES + 1;
  int*   cursor  = (int*)(ws + off); off += NODES;
  int*   bsum    = (int*)(ws + off); off += 256;
  int*   bbase   = (int*)(ws + off); off += 256;
  int*   col     = (int*)(ws + off); off += EDGES;

  // ---- CSR build ----
  hipMemsetAsync(cnt, 0, (size_t)NODES * sizeof(int), stream);
  k_hist<<<EDGES / 256, 256, 0, stream>>>(dst, cnt);
  k_scan_local<<<NODES / 256, 256, 0, stream>>>(cnt, rowptr, bsum);
  k_scan_base<<<1, 256, 0, stream>>>(bsum, bbase);
  k_scan_final<<<NODES / 256, 256, 0, stream>>>(rowptr, bbase, cursor);
  k_fill<<<EDGES / 256, 256, 0, stream>>>(src, dst, cursor, col);

  // ---- weight prep (independent) ----
  k_prep_wt2<<<128, 256, 0, stream>>>(W2rel, W2rt, Wt2);
  k_prep_norm2<<<1, 128, 0, stream>>>(p2w, rn2);

  // ---- layer 1 ----
  k_gather1<<<NODES / 16, 256, 0, stream>>>(x, rowptr, col, agg1);
  k_gemm1<<<NODES / 16, 128, 0, stream>>>(x, agg1, W1rel, b1, W1rt, p1w, h1, s1);
  k_topk<<<BATCH, 1024, 0, stream>>>(s1, nullptr, kept1, KP1);
  k_sx_readout1<<<BATCH * 8, 128, 0, stream>>>(h1, s1, kept1, psum1, pmax1);

  // ---- layer 2 (fused gather+GEMM) ----
  k_conv2<<<NODES / 64, 256, 0, stream>>>(h1, rowptr, col, kept1, Wt2, b2, p2w,
                                          rn2, h2, s2);
  k_topk<<<BATCH, 1024, 0, stream>>>(s2, kept1, kept2, KP2);
  k_readout2<<<BATCH * 8, 128, 0, stream>>>(h2, s2, kept2, psum2, pmax2);
  k_final<<<BATCH, 256, 0, stream>>>(psum1, pmax1, psum2, pmax2, out);
}

// Round 3
// 293.206 us; speedup vs baseline: 3.1764x; 1.8289x over previous
//
#include <hip/hip_runtime.h>
#include <cmath>

// Problem constants
#define BATCH   64
#define NPG     1024           // nodes per graph
#define NODES   65536          // BATCH*NPG
#define EDGES   524288
#define FIN     14
#define NH      128
#define KP1     820
#define KP2     656

// ---------------------------------------------------------------------------
// CSR build (by dst): histogram -> 2-level exclusive scan -> fill
// ---------------------------------------------------------------------------
__global__ __launch_bounds__(256) void k_hist(
    const int* __restrict__ dst, int* __restrict__ cnt) {
  int e = blockIdx.x * 256 + threadIdx.x;
  atomicAdd(&cnt[dst[e]], 1);
}

__global__ __launch_bounds__(256) void k_scan_local(
    const int* __restrict__ cnt, int* __restrict__ rowptr,
    int* __restrict__ bsum) {
  __shared__ int s[256];
  int t = threadIdx.x, b = blockIdx.x;
  int v = cnt[b * 256 + t];
  s[t] = v;
  __syncthreads();
  for (int d = 1; d < 256; d <<= 1) {
    int add = (t >= d) ? s[t - d] : 0;
    __syncthreads();
    s[t] += add;
    __syncthreads();
  }
  rowptr[b * 256 + t] = s[t] - v;      // exclusive, block-local
  if (t == 255) bsum[b] = s[255];
}

__global__ __launch_bounds__(256) void k_scan_base(
    const int* __restrict__ bsum, int* __restrict__ bbase) {
  __shared__ int s[256];
  int t = threadIdx.x;
  int v = bsum[t];
  s[t] = v;
  __syncthreads();
  for (int d = 1; d < 256; d <<= 1) {
    int add = (t >= d) ? s[t - d] : 0;
    __syncthreads();
    s[t] += add;
    __syncthreads();
  }
  bbase[t] = s[t] - v;                 // exclusive
}

__global__ __launch_bounds__(256) void k_scan_final(
    int* __restrict__ rowptr, const int* __restrict__ bbase,
    int* __restrict__ cursor) {
  int id = blockIdx.x * 256 + threadIdx.x;
  int v = rowptr[id] + bbase[blockIdx.x];
  rowptr[id] = v;
  cursor[id] = v;
  if (id == 0) rowptr[NODES] = EDGES;
}

__global__ __launch_bounds__(256) void k_fill(
    const int* __restrict__ src, const int* __restrict__ dst,
    int* __restrict__ cursor, int* __restrict__ col) {
  int e = blockIdx.x * 256 + threadIdx.x;
  int pos = atomicAdd(&cursor[dst[e]], 1);
  col[pos] = src[e];
}

// ---------------------------------------------------------------------------
// conv1 aggregation via CSR gather: agg1[n] = sum over incoming edges x[src]
// ---------------------------------------------------------------------------
__global__ __launch_bounds__(256) void k_gather1(
    const float* __restrict__ x, const int* __restrict__ rowptr,
    const int* __restrict__ col, float* __restrict__ agg1) {
  int t = threadIdx.x;
  int gi = t >> 4, l = t & 15;
  int n = blockIdx.x * 16 + gi;
  int rs = rowptr[n], re = rowptr[n + 1];
  if (l < FIN) {
    float acc = 0.f;
    for (int j = rs; j < re; ++j) {
      int v = col[j];
      acc += x[(size_t)v * FIN + l];
    }
    agg1[(size_t)n * FIN + l] = acc;
  }
}

// ---------------------------------------------------------------------------
// conv1 GEMM + relu + fused pool1 score
// ---------------------------------------------------------------------------
__global__ __launch_bounds__(128) void k_gemm1(
    const float* __restrict__ x, const float* __restrict__ agg1,
    const float* __restrict__ Wrel, const float* __restrict__ brel,
    const float* __restrict__ Wroot, const float* __restrict__ p1w,
    float* __restrict__ h1, float* __restrict__ s1) {
  __shared__ float Wl[128][29];
  __shared__ float arow[28];
  __shared__ float red[4];
  int t = threadIdx.x;
#pragma unroll
  for (int k = 0; k < FIN; ++k) {
    Wl[t][k]       = Wrel[t * FIN + k];
    Wl[t][FIN + k] = Wroot[t * FIN + k];
  }
  float p1 = p1w[t];
  float b  = brel[t];
  float q  = p1 * p1;
#pragma unroll
  for (int d = 32; d; d >>= 1) q += __shfl_xor(q, d);
  if ((t & 63) == 0) red[t >> 6] = q;
  __syncthreads();
  float rnorm = rsqrtf(red[0] + red[1]);

  int n0 = blockIdx.x * 16;
  for (int i = 0; i < 16; ++i) {
    int n = n0 + i;
    __syncthreads();
    if (t < FIN)            arow[t] = agg1[(size_t)n * FIN + t];
    else if (t < 2 * FIN)   arow[t] = x[(size_t)n * FIN + (t - FIN)];
    __syncthreads();
    float acc = b;
#pragma unroll
    for (int k = 0; k < 2 * FIN; ++k) acc += Wl[t][k] * arow[k];
    acc = fmaxf(acc, 0.f);
    h1[(size_t)n * NH + t] = acc;
    float pp = acc * p1;
#pragma unroll
    for (int d = 32; d; d >>= 1) pp += __shfl_xor(pp, d);
    if ((t & 63) == 0) red[2 + (t >> 6)] = pp;
    __syncthreads();
    if (t == 0) s1[n] = tanhf((red[2] + red[3]) * rnorm);
  }
}

// ---------------------------------------------------------------------------
// exact per-graph top-K via bitonic sort
// ---------------------------------------------------------------------------
__global__ __launch_bounds__(1024) void k_topk(
    const float* __restrict__ score, const int* __restrict__ mask_in,
    int* __restrict__ kept, int K) {
  __shared__ unsigned long long keys[1024];
  int t = threadIdx.x;
  int g = blockIdx.x;
  int n = g * NPG + t;
  unsigned int inv;
  if (mask_in && !mask_in[n]) {
    inv = 0xFFFFFFFFu;
  } else {
    unsigned int u   = __float_as_uint(score[n]);
    unsigned int ord = (u & 0x80000000u) ? ~u : (u | 0x80000000u);
    inv = ~ord;
  }
  keys[t] = ((unsigned long long)inv << 32) | (unsigned int)t;
  __syncthreads();
  for (int k = 2; k <= 1024; k <<= 1) {
    for (int j = k >> 1; j > 0; j >>= 1) {
      int ixj = t ^ j;
      if (ixj > t) {
        unsigned long long a = keys[t], b = keys[ixj];
        bool up = ((t & k) == 0);
        if ((a > b) == up) { keys[t] = b; keys[ixj] = a; }
      }
      __syncthreads();
    }
  }
  int idx = (int)(keys[t] & 0xFFFFFFFFu);
  kept[g * NPG + idx] = (t < K) ? 1 : 0;
}

// ---------------------------------------------------------------------------
// pool1 apply + readout1 partials (8 chunks of 128 nodes per graph)
// ---------------------------------------------------------------------------
__global__ __launch_bounds__(128) void k_sx_readout1(
    float* __restrict__ h1, const float* __restrict__ s1,
    const int* __restrict__ kept1, float* __restrict__ psum,
    float* __restrict__ pmax) {
  int g = blockIdx.x >> 3, c = blockIdx.x & 7;
  int f = threadIdx.x;
  int nbase = g * NPG + c * 128;
  float sum = 0.f, mx = -1e30f;
  for (int i = 0; i < 128; ++i) {
    int n = nbase + i;
    float v = 0.f;
    if (kept1[n]) {
      v = h1[(size_t)n * NH + f] * s1[n];
      sum += v;
      mx = fmaxf(mx, v);
    }
    h1[(size_t)n * NH + f] = v;   // becomes sx
  }
  psum[(size_t)blockIdx.x * NH + f] = sum;
  pmax[(size_t)blockIdx.x * NH + f] = mx;
}

// ---------------------------------------------------------------------------
// prep for conv2 GEMM: Wt[k][o] = k<128 ? W2rel[o][k] : W2root[o][k-128]
// ---------------------------------------------------------------------------
__global__ __launch_bounds__(256) void k_prep_wt2(
    const float* __restrict__ Wrel, const float* __restrict__ Wroot,
    float* __restrict__ Wt) {
  int id = blockIdx.x * 256 + threadIdx.x;
  int k = id >> 7, o = id & 127;
  Wt[id] = (k < NH) ? Wrel[o * NH + k] : Wroot[o * NH + (k - NH)];
}

__global__ __launch_bounds__(128) void k_prep_norm2(
    const float* __restrict__ p2w, float* __restrict__ rnorm2) {
  __shared__ float red[2];
  int t = threadIdx.x;
  float q = p2w[t] * p2w[t];
#pragma unroll
  for (int d = 32; d; d >>= 1) q += __shfl_xor(q, d);
  if ((t & 63) == 0) red[t >> 6] = q;
  __syncthreads();
  if (t == 0) *rnorm2 = rsqrtf(red[0] + red[1]);
}

// ---------------------------------------------------------------------------
// conv2 aggregation, CSR gather, ONE WAVE PER DST ROW.
// col indices preloaded into lanes and broadcast via shfl (no dependent
// col->sx chain); 4-edge unroll gives 4 independent 512B loads in flight.
// Rows with dropped dst are skipped entirely (their h2/s2 are masked later).
// ---------------------------------------------------------------------------
__global__ __launch_bounds__(256) void k_gather2(
    const float* __restrict__ sx, const int* __restrict__ rowptr,
    const int* __restrict__ col, const int* __restrict__ kept1,
    float* __restrict__ agg2) {
  int wave = threadIdx.x >> 6, lane = threadIdx.x & 63;
  int d = blockIdx.x * 4 + wave;
  if (!kept1[d]) return;                 // row never consumed downstream
  int rs = rowptr[d], re = rowptr[d + 1];
  int deg = re - rs;
  int colv = (lane < deg) ? col[rs + lane] : 0;
  int m = deg < 64 ? deg : 64;
  float ax = 0.f, ay = 0.f;
  int nfull = m & ~3;
  int j = 0;
  for (; j < nfull; j += 4) {
    int v0 = __shfl(colv, j);
    int v1 = __shfl(colv, j + 1);
    int v2 = __shfl(colv, j + 2);
    int v3 = __shfl(colv, j + 3);
    float2 a = *(const float2*)(sx + (size_t)v0 * NH + lane * 2);
    float2 b = *(const float2*)(sx + (size_t)v1 * NH + lane * 2);
    float2 c = *(const float2*)(sx + (size_t)v2 * NH + lane * 2);
    float2 e = *(const float2*)(sx + (size_t)v3 * NH + lane * 2);
    ax += a.x + b.x + c.x + e.x;
    ay += a.y + b.y + c.y + e.y;
  }
  for (; j < m; ++j) {
    int v = __shfl(colv, j);
    float2 a = *(const float2*)(sx + (size_t)v * NH + lane * 2);
    ax += a.x; ay += a.y;
  }
  for (int jj = rs + 64; jj < re; ++jj) {  // deg>64 fallback (≈never)
    int v = col[jj];
    float2 a = *(const float2*)(sx + (size_t)v * NH + lane * 2);
    ax += a.x; ay += a.y;
  }
  *(float2*)(agg2 + (size_t)d * NH + lane * 2) = make_float2(ax, ay);
}

// ---------------------------------------------------------------------------
// conv2 GEMM (K=256 from [agg2|sx]) + bias + relu + fused pool2 score.
// Block = 256 threads, 64 nodes x 128 outs; thread = 4 nodes x 8 outs.
// h2 may ALIAS agg2: each block reads only its own 64 rows of agg2 (kc<8)
// before writing the same 64 rows of h2 in the epilogue.
// ---------------------------------------------------------------------------
__global__ __launch_bounds__(256) void k_gemm2(
    const float* __restrict__ agg2, const float* __restrict__ sx,
    const float* __restrict__ Wt, const float* __restrict__ b2,
    const float* __restrict__ p2w, const float* __restrict__ rnorm2p,
    float* __restrict__ h2, float* __restrict__ s2) {
  __shared__ float Al[64][17];
  __shared__ float Wl[16 * 128];
  int t = threadIdx.x;
  int nb = blockIdx.x * 64;
  int og = t & 15;
  int ng = t >> 4;
  float acc[4][8];
#pragma unroll
  for (int i = 0; i < 4; ++i)
#pragma unroll
    for (int j = 0; j < 8; ++j) acc[i][j] = 0.f;

  int lrow = t >> 2, lcol = (t & 3) * 4;
  for (int kc = 0; kc < 16; ++kc) {
    __syncthreads();
    const float* srcA = (kc < 8) ? agg2 : sx;
    int kbase = (kc & 7) * 16;
    float4 av = *(const float4*)(srcA + (size_t)(nb + lrow) * NH + kbase + lcol);
    Al[lrow][lcol + 0] = av.x;
    Al[lrow][lcol + 1] = av.y;
    Al[lrow][lcol + 2] = av.z;
    Al[lrow][lcol + 3] = av.w;
    *(float4*)&Wl[t * 8]     = *(const float4*)(Wt + kc * 2048 + t * 8);
    *(float4*)&Wl[t * 8 + 4] = *(const float4*)(Wt + kc * 2048 + t * 8 + 4);
    __syncthreads();
#pragma unroll
    for (int kk = 0; kk < 16; ++kk) {
      float a0 = Al[ng * 4 + 0][kk];
      float a1 = Al[ng * 4 + 1][kk];
      float a2 = Al[ng * 4 + 2][kk];
      float a3 = Al[ng * 4 + 3][kk];
      float4 w0 = *(const float4*)&Wl[kk * 128 + og * 8];
      float4 w1 = *(const float4*)&Wl[kk * 128 + og * 8 + 4];
      float w[8] = {w0.x, w0.y, w0.z, w0.w, w1.x, w1.y, w1.z, w1.w};
#pragma unroll
      for (int j = 0; j < 8; ++j) {
        acc[0][j] += a0 * w[j];
        acc[1][j] += a1 * w[j];
        acc[2][j] += a2 * w[j];
        acc[3][j] += a3 * w[j];
      }
    }
  }

  float rnorm = *rnorm2p;
  float bb[8], pw[8];
#pragma unroll
  for (int j = 0; j < 8; ++j) {
    bb[j] = b2[og * 8 + j];
    pw[j] = p2w[og * 8 + j];
  }
#pragma unroll
  for (int i = 0; i < 4; ++i) {
    int n = nb + ng * 4 + i;
    float pv = 0.f;
#pragma unroll
    for (int j = 0; j < 8; ++j) {
      float v = fmaxf(acc[i][j] + bb[j], 0.f);
      acc[i][j] = v;
      pv += v * pw[j];
    }
    *(float4*)(h2 + (size_t)n * NH + og * 8) =
        make_float4(acc[i][0], acc[i][1], acc[i][2], acc[i][3]);
    *(float4*)(h2 + (size_t)n * NH + og * 8 + 4) =
        make_float4(acc[i][4], acc[i][5], acc[i][6], acc[i][7]);
    pv += __shfl_xor(pv, 1);
    pv += __shfl_xor(pv, 2);
    pv += __shfl_xor(pv, 4);
    pv += __shfl_xor(pv, 8);
    if (og == 0) s2[n] = tanhf(pv * rnorm);
  }
}

// ---------------------------------------------------------------------------
// readout2 partials over kept2 nodes (8 chunks of 128 nodes per graph)
// ---------------------------------------------------------------------------
__global__ __launch_bounds__(128) void k_readout2(
    const float* __restrict__ h2, const float* __restrict__ s2,
    const int* __restrict__ kept2, float* __restrict__ psum,
    float* __restrict__ pmax) {
  int g = blockIdx.x >> 3, c = blockIdx.x & 7;
  int f = threadIdx.x;
  int nbase = g * NPG + c * 128;
  float sum = 0.f, mx = -1e30f;
  for (int i = 0; i < 128; ++i) {
    int n = nbase + i;
    if (kept2[n]) {
      float v = h2[(size_t)n * NH + f] * s2[n];
      sum += v;
      mx = fmaxf(mx, v);
    }
  }
  psum[(size_t)blockIdx.x * NH + f] = sum;
  pmax[(size_t)blockIdx.x * NH + f] = mx;
}

// ---------------------------------------------------------------------------
// final combine (8 chunks per graph)
// ---------------------------------------------------------------------------
__global__ __launch_bounds__(256) void k_final(
    const float* __restrict__ psum1, const float* __restrict__ pmax1,
    const float* __restrict__ psum2, const float* __restrict__ pmax2,
    float* __restrict__ out) {
  int g = blockIdx.x, t = threadIdx.x;
  if (t < 128) {
    float a = 0.f, b = 0.f;
#pragma unroll
    for (int c = 0; c < 8; ++c) {
      a += psum1[(size_t)(g * 8 + c) * NH + t];
      b += psum2[(size_t)(g * 8 + c) * NH + t];
    }
    out[(size_t)g * 256 + t] = a / (float)KP1 + b / (float)KP2;
  } else {
    int f = t - 128;
    float a = -1e30f, b = -1e30f;
#pragma unroll
    for (int c = 0; c < 8; ++c) {
      a = fmaxf(a, pmax1[(size_t)(g * 8 + c) * NH + f]);
      b = fmaxf(b, pmax2[(size_t)(g * 8 + c) * NH + f]);
    }
    out[(size_t)g * 256 + t] = a + b;
  }
}

// ---------------------------------------------------------------------------
extern "C" void kernel_launch(void* const* d_in, const int* in_sizes, int n_in,
                              void* d_out, int out_size, void* d_ws, size_t ws_size,
                              hipStream_t stream) {
  const float* x     = (const float*)d_in[0];
  const int*   eidx  = (const int*)d_in[1];
  const int*   src   = eidx;
  const int*   dst   = eidx + EDGES;
  const float* W1rel = (const float*)d_in[3];
  const float* b1    = (const float*)d_in[4];
  const float* W1rt  = (const float*)d_in[5];
  const float* p1w   = (const float*)d_in[6];
  const float* W2rel = (const float*)d_in[7];
  const float* b2    = (const float*)d_in[8];
  const float* W2rt  = (const float*)d_in[9];
  const float* p2w   = (const float*)d_in[10];
  float* out = (float*)d_out;

  // workspace layout (floats) — h2 aliases agg2 (see k_gemm2)
  float* ws = (float*)d_ws;
  size_t off = 0;
  float* h1    = ws + off; off += (size_t)NODES * NH;   // h1, then sx in place
  float* agg2  = ws + off; off += (size_t)NODES * NH;   // then h2 in place
  float* h2    = agg2;
  float* agg1  = ws + off; off += (size_t)NODES * FIN;
  float* s1    = ws + off; off += NODES;
  float* s2    = ws + off; off += NODES;
  int*   kept1 = (int*)(ws + off); off += NODES;
  int*   kept2 = (int*)(ws + off); off += NODES;
  float* psum1 = ws + off; off += 512 * NH;
  float* pmax1 = ws + off; off += 512 * NH;
  float* psum2 = ws + off; off += 512 * NH;
  float* pmax2 = ws + off; off += 512 * NH;
  float* Wt2   = ws + off; off += 256 * NH;
  float* rn2   = ws + off; off += 1;
  int*   cnt     = (int*)(ws + off); off += NODES;
  int*   rowptr  = (int*)(ws + off); off += NODES + 1;
  int*   cursor  = (int*)(ws + off); off += NODES;
  int*   bsum    = (int*)(ws + off); off += 256;
  int*   bbase   = (int*)(ws + off); off += 256;
  int*   col     = (int*)(ws + off); off += EDGES;

  // ---- CSR build ----
  hipMemsetAsync(cnt, 0, (size_t)NODES * sizeof(int), stream);
  k_hist<<<EDGES / 256, 256, 0, stream>>>(dst, cnt);
  k_scan_local<<<NODES / 256, 256, 0, stream>>>(cnt, rowptr, bsum);
  k_scan_base<<<1, 256, 0, stream>>>(bsum, bbase);
  k_scan_final<<<NODES / 256, 256, 0, stream>>>(rowptr, bbase, cursor);
  k_fill<<<EDGES / 256, 256, 0, stream>>>(src, dst, cursor, col);

  // ---- weight prep (independent) ----
  k_prep_wt2<<<128, 256, 0, stream>>>(W2rel, W2rt, Wt2);
  k_prep_norm2<<<1, 128, 0, stream>>>(p2w, rn2);

  // ---- layer 1 ----
  k_gather1<<<NODES / 16, 256, 0, stream>>>(x, rowptr, col, agg1);
  k_gemm1<<<NODES / 16, 128, 0, stream>>>(x, agg1, W1rel, b1, W1rt, p1w, h1, s1);
  k_topk<<<BATCH, 1024, 0, stream>>>(s1, nullptr, kept1, KP1);
  k_sx_readout1<<<BATCH * 8, 128, 0, stream>>>(h1, s1, kept1, psum1, pmax1);

  // ---- layer 2 (gather then GEMM) ----
  k_gather2<<<NODES / 4, 256, 0, stream>>>(h1, rowptr, col, kept1, agg2);
  k_gemm2<<<NODES / 64, 256, 0, stream>>>(agg2, h1, Wt2, b2, p2w, rn2, h2, s2);
  k_topk<<<BATCH, 1024, 0, stream>>>(s2, kept1, kept2, KP2);
  k_readout2<<<BATCH * 8, 128, 0, stream>>>(h2, s2, kept2, psum2, pmax2);
  k_final<<<BATCH, 256, 0, stream>>>(psum1, pmax1, psum2, pmax2, out);
}

// Round 4
// 266.978 us; speedup vs baseline: 3.4884x; 1.0982x over previous
//
#include <hip/hip_runtime.h>
#include <cmath>

// Problem constants
#define BATCH   64
#define NPG     1024           // nodes per graph
#define NODES   65536          // BATCH*NPG
#define EDGES   524288
#define FIN     14
#define NH      128
#define KP1     820
#define KP2     656

// ---------------------------------------------------------------------------
// CSR build (by dst): histogram -> 2-level exclusive scan -> fill
// ---------------------------------------------------------------------------
__global__ __launch_bounds__(256) void k_hist(
    const int* __restrict__ dst, int* __restrict__ cnt) {
  int e = blockIdx.x * 256 + threadIdx.x;
  atomicAdd(&cnt[dst[e]], 1);
}

__global__ __launch_bounds__(256) void k_scan_local(
    const int* __restrict__ cnt, int* __restrict__ rowptr,
    int* __restrict__ bsum) {
  __shared__ int s[256];
  int t = threadIdx.x, b = blockIdx.x;
  int v = cnt[b * 256 + t];
  s[t] = v;
  __syncthreads();
  for (int d = 1; d < 256; d <<= 1) {
    int add = (t >= d) ? s[t - d] : 0;
    __syncthreads();
    s[t] += add;
    __syncthreads();
  }
  rowptr[b * 256 + t] = s[t] - v;      // exclusive, block-local
  if (t == 255) bsum[b] = s[255];
}

__global__ __launch_bounds__(256) void k_scan_base(
    const int* __restrict__ bsum, int* __restrict__ bbase) {
  __shared__ int s[256];
  int t = threadIdx.x;
  int v = bsum[t];
  s[t] = v;
  __syncthreads();
  for (int d = 1; d < 256; d <<= 1) {
    int add = (t >= d) ? s[t - d] : 0;
    __syncthreads();
    s[t] += add;
    __syncthreads();
  }
  bbase[t] = s[t] - v;                 // exclusive
}

__global__ __launch_bounds__(256) void k_scan_final(
    int* __restrict__ rowptr, const int* __restrict__ bbase,
    int* __restrict__ cursor) {
  int id = blockIdx.x * 256 + threadIdx.x;
  int v = rowptr[id] + bbase[blockIdx.x];
  rowptr[id] = v;
  cursor[id] = v;
  if (id == 0) rowptr[NODES] = EDGES;
}

__global__ __launch_bounds__(256) void k_fill(
    const int* __restrict__ src, const int* __restrict__ dst,
    int* __restrict__ cursor, int* __restrict__ col) {
  int e = blockIdx.x * 256 + threadIdx.x;
  int pos = atomicAdd(&cursor[dst[e]], 1);
  col[pos] = src[e];
}

// ---------------------------------------------------------------------------
// generic: rnorm = 1/||w||  (w has 128 elems)
// ---------------------------------------------------------------------------
__global__ __launch_bounds__(128) void k_prep_norm(
    const float* __restrict__ w, float* __restrict__ rnorm) {
  __shared__ float red[2];
  int t = threadIdx.x;
  float q = w[t] * w[t];
#pragma unroll
  for (int d = 32; d; d >>= 1) q += __shfl_xor(q, d);
  if ((t & 63) == 0) red[t >> 6] = q;
  __syncthreads();
  if (t == 0) *rnorm = rsqrtf(red[0] + red[1]);
}

// ---------------------------------------------------------------------------
// prep for conv2 GEMM: Wt[k][o] = k<128 ? W2rel[o][k] : W2root[o][k-128]
// ---------------------------------------------------------------------------
__global__ __launch_bounds__(256) void k_prep_wt2(
    const float* __restrict__ Wrel, const float* __restrict__ Wroot,
    float* __restrict__ Wt) {
  int id = blockIdx.x * 256 + threadIdx.x;
  int k = id >> 7, o = id & 127;
  Wt[id] = (k < NH) ? Wrel[o * NH + k] : Wroot[o * NH + (k - NH)];
}

// ---------------------------------------------------------------------------
// conv1 aggregation via CSR gather (XCD-swizzled for per-graph L2 locality)
// ---------------------------------------------------------------------------
__global__ __launch_bounds__(256) void k_gather1(
    const float* __restrict__ x, const int* __restrict__ rowptr,
    const int* __restrict__ col, float* __restrict__ agg1) {
  int bid = blockIdx.x;                       // 4096 blocks, 512 per XCD chunk
  int swz = (bid & 7) * 512 + (bid >> 3);
  int t = threadIdx.x;
  int gi = t >> 4, l = t & 15;
  int n = swz * 16 + gi;
  int rs = rowptr[n], re = rowptr[n + 1];
  if (l < FIN) {
    float acc = 0.f;
    for (int j = rs; j < re; ++j) {
      int v = col[j];
      acc += x[(size_t)v * FIN + l];
    }
    agg1[(size_t)n * FIN + l] = acc;
  }
}

// ---------------------------------------------------------------------------
// conv1 GEMM + relu + fused pool1 score.
// Block 256 thr / 64 nodes; thread = 4 nodes x 8 outs (cols og*4+j, 64+og*4+j)
// ---------------------------------------------------------------------------
__global__ __launch_bounds__(256) void k_gemm1(
    const float* __restrict__ x, const float* __restrict__ agg1,
    const float* __restrict__ Wrel, const float* __restrict__ brel,
    const float* __restrict__ Wroot, const float* __restrict__ p1w,
    const float* __restrict__ rn1p, float* __restrict__ h1,
    float* __restrict__ s1) {
  __shared__ float As[64 * FIN];
  __shared__ float Xs[64 * FIN];
  __shared__ float Wl[2 * FIN][NH];
  int t = threadIdx.x;
  int nb = blockIdx.x * 64;
  for (int i = t; i < 64 * FIN; i += 256) {
    As[i] = agg1[(size_t)nb * FIN + i];
    Xs[i] = x[(size_t)nb * FIN + i];
  }
  for (int i = t; i < NH * FIN; i += 256) {
    int o = i / FIN, k = i - o * FIN;
    Wl[k][o]       = Wrel[i];
    Wl[k + FIN][o] = Wroot[i];
  }
  __syncthreads();
  int og = t & 15, ng = t >> 4, ra = ng * 4;
  float bb[8], pw[8];
#pragma unroll
  for (int j = 0; j < 4; ++j) {
    int c0 = og * 4 + j, c1 = 64 + og * 4 + j;
    bb[j] = brel[c0]; bb[j + 4] = brel[c1];
    pw[j] = p1w[c0];  pw[j + 4] = p1w[c1];
  }
  float acc[4][8];
#pragma unroll
  for (int i = 0; i < 4; ++i)
#pragma unroll
    for (int j = 0; j < 8; ++j) acc[i][j] = bb[j];
#pragma unroll
  for (int k = 0; k < FIN; ++k) {
    float4 w0 = *(const float4*)&Wl[k][og * 4];
    float4 w1 = *(const float4*)&Wl[k][64 + og * 4];
#pragma unroll
    for (int i = 0; i < 4; ++i) {
      float a = As[(ra + i) * FIN + k];
      acc[i][0] += a * w0.x; acc[i][1] += a * w0.y;
      acc[i][2] += a * w0.z; acc[i][3] += a * w0.w;
      acc[i][4] += a * w1.x; acc[i][5] += a * w1.y;
      acc[i][6] += a * w1.z; acc[i][7] += a * w1.w;
    }
  }
#pragma unroll
  for (int k = 0; k < FIN; ++k) {
    float4 w0 = *(const float4*)&Wl[FIN + k][og * 4];
    float4 w1 = *(const float4*)&Wl[FIN + k][64 + og * 4];
#pragma unroll
    for (int i = 0; i < 4; ++i) {
      float a = Xs[(ra + i) * FIN + k];
      acc[i][0] += a * w0.x; acc[i][1] += a * w0.y;
      acc[i][2] += a * w0.z; acc[i][3] += a * w0.w;
      acc[i][4] += a * w1.x; acc[i][5] += a * w1.y;
      acc[i][6] += a * w1.z; acc[i][7] += a * w1.w;
    }
  }
  float rnorm = *rn1p;
#pragma unroll
  for (int i = 0; i < 4; ++i) {
    int n = nb + ra + i;
    float pv = 0.f;
#pragma unroll
    for (int j = 0; j < 8; ++j) {
      float v = fmaxf(acc[i][j], 0.f);
      acc[i][j] = v;
      pv += v * pw[j];
    }
    *(float4*)(h1 + (size_t)n * NH + og * 4) =
        make_float4(acc[i][0], acc[i][1], acc[i][2], acc[i][3]);
    *(float4*)(h1 + (size_t)n * NH + 64 + og * 4) =
        make_float4(acc[i][4], acc[i][5], acc[i][6], acc[i][7]);
    pv += __shfl_xor(pv, 1);
    pv += __shfl_xor(pv, 2);
    pv += __shfl_xor(pv, 4);
    pv += __shfl_xor(pv, 8);
    if (og == 0) s1[n] = tanhf(pv * rnorm);
  }
}

// ---------------------------------------------------------------------------
// exact per-graph top-K: 512 threads, all-active bitonic over 1024 keys
// ---------------------------------------------------------------------------
__global__ __launch_bounds__(512) void k_topk(
    const float* __restrict__ score, const int* __restrict__ mask_in,
    int* __restrict__ kept, int K) {
  __shared__ unsigned long long keys[1024];
  int t = threadIdx.x, g = blockIdx.x;
  for (int i = t; i < 1024; i += 512) {
    int n = g * NPG + i;
    unsigned int inv;
    if (mask_in && !mask_in[n]) {
      inv = 0xFFFFFFFFu;
    } else {
      unsigned int u   = __float_as_uint(score[n]);
      unsigned int ord = (u & 0x80000000u) ? ~u : (u | 0x80000000u);
      inv = ~ord;
    }
    keys[i] = ((unsigned long long)inv << 32) | (unsigned int)i;
  }
  __syncthreads();
  for (int k = 2; k <= 1024; k <<= 1) {
    for (int j = k >> 1; j > 0; j >>= 1) {
      int i = ((t & ~(j - 1)) << 1) | (t & (j - 1));
      int p = i | j;
      unsigned long long a = keys[i], b = keys[p];
      bool up = ((i & k) == 0);
      if ((a > b) == up) { keys[i] = b; keys[p] = a; }
      __syncthreads();
    }
  }
  for (int i = t; i < 1024; i += 512) {
    int idx = (int)(keys[i] & 0xFFFFFFFFu);
    kept[g * NPG + idx] = (i < K) ? 1 : 0;
  }
}

// ---------------------------------------------------------------------------
// readout partials over kept nodes: v = h[n]*s[n]  (read-only)
// ---------------------------------------------------------------------------
__global__ __launch_bounds__(128) void k_readout(
    const float* __restrict__ h, const float* __restrict__ s,
    const int* __restrict__ kept, float* __restrict__ psum,
    float* __restrict__ pmax) {
  int g = blockIdx.x >> 3, c = blockIdx.x & 7;
  int f = threadIdx.x;
  int nbase = g * NPG + c * 128;
  float sum = 0.f, mx = -1e30f;
  for (int i = 0; i < 128; ++i) {
    int n = nbase + i;
    if (kept[n]) {
      float v = h[(size_t)n * NH + f] * s[n];
      sum += v;
      mx = fmaxf(mx, v);
    }
  }
  psum[(size_t)blockIdx.x * NH + f] = sum;
  pmax[(size_t)blockIdx.x * NH + f] = mx;
}

// ---------------------------------------------------------------------------
// conv2 aggregation: one wave per kept dst row; scale s1*kept applied on the
// fly (sx never materialized). XCD-swizzled: graph-local L2 reuse of h1 rows.
// ---------------------------------------------------------------------------
__global__ __launch_bounds__(256) void k_gather2(
    const float* __restrict__ h1, const float* __restrict__ s1,
    const int* __restrict__ rowptr, const int* __restrict__ col,
    const int* __restrict__ kept1, float* __restrict__ agg2) {
  int bid = blockIdx.x;                       // 16384 blocks, 2048 per XCD
  int swz = (bid & 7) * 2048 + (bid >> 3);
  int wave = threadIdx.x >> 6, lane = threadIdx.x & 63;
  int d = swz * 4 + wave;
  if (!kept1[d]) return;                      // row never consumed downstream
  int rs = rowptr[d], re = rowptr[d + 1];
  int deg = re - rs;
  int colv = 0; float sv = 0.f;
  if (lane < deg) {
    colv = col[rs + lane];
    sv = kept1[colv] ? s1[colv] : 0.f;
  }
  int m = deg < 64 ? deg : 64;
  float ax = 0.f, ay = 0.f;
  int nfull = m & ~3;
  int j = 0;
  for (; j < nfull; j += 4) {
    int v0 = __shfl(colv, j);
    int v1 = __shfl(colv, j + 1);
    int v2 = __shfl(colv, j + 2);
    int v3 = __shfl(colv, j + 3);
    float f0 = __shfl(sv, j);
    float f1 = __shfl(sv, j + 1);
    float f2 = __shfl(sv, j + 2);
    float f3 = __shfl(sv, j + 3);
    float2 a = *(const float2*)(h1 + (size_t)v0 * NH + lane * 2);
    float2 b = *(const float2*)(h1 + (size_t)v1 * NH + lane * 2);
    float2 c = *(const float2*)(h1 + (size_t)v2 * NH + lane * 2);
    float2 e = *(const float2*)(h1 + (size_t)v3 * NH + lane * 2);
    ax += a.x * f0 + b.x * f1 + c.x * f2 + e.x * f3;
    ay += a.y * f0 + b.y * f1 + c.y * f2 + e.y * f3;
  }
  for (; j < m; ++j) {
    int v = __shfl(colv, j);
    float f = __shfl(sv, j);
    float2 a = *(const float2*)(h1 + (size_t)v * NH + lane * 2);
    ax += a.x * f; ay += a.y * f;
  }
  for (int jj = rs + 64; jj < re; ++jj) {      // deg>64 fallback (≈never)
    int v = col[jj];
    float f = kept1[v] ? s1[v] : 0.f;
    float2 a = *(const float2*)(h1 + (size_t)v * NH + lane * 2);
    ax += a.x * f; ay += a.y * f;
  }
  *(float2*)(agg2 + (size_t)d * NH + lane * 2) = make_float2(ax, ay);
}

// ---------------------------------------------------------------------------
// conv2 GEMM (K=256 = [agg2 | h1*s1*kept]) + bias + relu + fused pool2 score.
// Thread = 4 nodes x 8 outs at cols og*4+j and 64+og*4+j (2-way LDS, free).
// K-chunk 32 -> 8 iterations, 16 barriers. h2 ALIASES agg2 (own rows only).
// ---------------------------------------------------------------------------
__global__ __launch_bounds__(256) void k_gemm2(
    const float* __restrict__ agg2, const float* __restrict__ h1,
    const float* __restrict__ s1, const int* __restrict__ kept1,
    const float* __restrict__ Wt, const float* __restrict__ b2,
    const float* __restrict__ p2w, const float* __restrict__ rnorm2p,
    float* __restrict__ h2, float* __restrict__ s2) {
  __shared__ float Al[64][36];          // K-chunk tile, stride 36 (16B aligned)
  __shared__ float Wl[32 * NH];         // 16 KB
  __shared__ float rs_l[64];            // s1*kept per row
  __shared__ float ms_l[64];            // kept mask per row (caps garbage)
  int t = threadIdx.x;
  int nb = blockIdx.x * 64;
  if (t < 64) {
    int k = kept1[nb + t];
    ms_l[t] = k ? 1.f : 0.f;
    rs_l[t] = k ? s1[nb + t] : 0.f;
  }
  int og = t & 15, ng = t >> 4, ra = ng * 4;
  float acc[4][8];
#pragma unroll
  for (int i = 0; i < 4; ++i)
#pragma unroll
    for (int j = 0; j < 8; ++j) acc[i][j] = 0.f;

  int r0s = t >> 3, c0s = (t & 7) * 4;        // stage rows 0..31
  int r1s = r0s + 32;                          // stage rows 32..63
  for (int kc = 0; kc < 8; ++kc) {
    __syncthreads();
    if (kc < 4) {
      int kbase = kc * 32;
      float4 v0 = *(const float4*)(agg2 + (size_t)(nb + r0s) * NH + kbase + c0s);
      float4 v1 = *(const float4*)(agg2 + (size_t)(nb + r1s) * NH + kbase + c0s);
      float m0 = ms_l[r0s], m1 = ms_l[r1s];
      v0.x *= m0; v0.y *= m0; v0.z *= m0; v0.w *= m0;
      v1.x *= m1; v1.y *= m1; v1.z *= m1; v1.w *= m1;
      *(float4*)&Al[r0s][c0s] = v0;
      *(float4*)&Al[r1s][c0s] = v1;
    } else {
      int kbase = (kc - 4) * 32;
      float4 v0 = *(const float4*)(h1 + (size_t)(nb + r0s) * NH + kbase + c0s);
      float4 v1 = *(const float4*)(h1 + (size_t)(nb + r1s) * NH + kbase + c0s);
      float sc0 = rs_l[r0s], sc1 = rs_l[r1s];
      v0.x *= sc0; v0.y *= sc0; v0.z *= sc0; v0.w *= sc0;
      v1.x *= sc1; v1.y *= sc1; v1.z *= sc1; v1.w *= sc1;
      *(float4*)&Al[r0s][c0s] = v0;
      *(float4*)&Al[r1s][c0s] = v1;
    }
    {
      const float4* wsrc = (const float4*)(Wt + (size_t)kc * 32 * NH);
      float4* wdst = (float4*)Wl;
      wdst[t]       = wsrc[t];
      wdst[t + 256] = wsrc[t + 256];
      wdst[t + 512] = wsrc[t + 512];
      wdst[t + 768] = wsrc[t + 768];
    }
    __syncthreads();
#pragma unroll
    for (int kk = 0; kk < 32; ++kk) {
      float4 w0 = *(const float4*)&Wl[kk * NH + og * 4];
      float4 w1 = *(const float4*)&Wl[kk * NH + 64 + og * 4];
      float a0 = Al[ra + 0][kk];
      float a1 = Al[ra + 1][kk];
      float a2 = Al[ra + 2][kk];
      float a3 = Al[ra + 3][kk];
      acc[0][0] += a0 * w0.x; acc[0][1] += a0 * w0.y;
      acc[0][2] += a0 * w0.z; acc[0][3] += a0 * w0.w;
      acc[0][4] += a0 * w1.x; acc[0][5] += a0 * w1.y;
      acc[0][6] += a0 * w1.z; acc[0][7] += a0 * w1.w;
      acc[1][0] += a1 * w0.x; acc[1][1] += a1 * w0.y;
      acc[1][2] += a1 * w0.z; acc[1][3] += a1 * w0.w;
      acc[1][4] += a1 * w1.x; acc[1][5] += a1 * w1.y;
      acc[1][6] += a1 * w1.z; acc[1][7] += a1 * w1.w;
      acc[2][0] += a2 * w0.x; acc[2][1] += a2 * w0.y;
      acc[2][2] += a2 * w0.z; acc[2][3] += a2 * w0.w;
      acc[2][4] += a2 * w1.x; acc[2][5] += a2 * w1.y;
      acc[2][6] += a2 * w1.z; acc[2][7] += a2 * w1.w;
      acc[3][0] += a3 * w0.x; acc[3][1] += a3 * w0.y;
      acc[3][2] += a3 * w0.z; acc[3][3] += a3 * w0.w;
      acc[3][4] += a3 * w1.x; acc[3][5] += a3 * w1.y;
      acc[3][6] += a3 * w1.z; acc[3][7] += a3 * w1.w;
    }
  }

  float rnorm = *rnorm2p;
  float bb[8], pw[8];
#pragma unroll
  for (int j = 0; j < 4; ++j) {
    int c0 = og * 4 + j, c1 = 64 + og * 4 + j;
    bb[j] = b2[c0]; bb[j + 4] = b2[c1];
    pw[j] = p2w[c0]; pw[j + 4] = p2w[c1];
  }
#pragma unroll
  for (int i = 0; i < 4; ++i) {
    int n = nb + ra + i;
    float pv = 0.f;
#pragma unroll
    for (int j = 0; j < 8; ++j) {
      float v = fmaxf(acc[i][j] + bb[j], 0.f);
      acc[i][j] = v;
      pv += v * pw[j];
    }
    *(float4*)(h2 + (size_t)n * NH + og * 4) =
        make_float4(acc[i][0], acc[i][1], acc[i][2], acc[i][3]);
    *(float4*)(h2 + (size_t)n * NH + 64 + og * 4) =
        make_float4(acc[i][4], acc[i][5], acc[i][6], acc[i][7]);
    pv += __shfl_xor(pv, 1);
    pv += __shfl_xor(pv, 2);
    pv += __shfl_xor(pv, 4);
    pv += __shfl_xor(pv, 8);
    if (og == 0) s2[n] = tanhf(pv * rnorm);
  }
}

// ---------------------------------------------------------------------------
// final combine (8 chunks per graph)
// ---------------------------------------------------------------------------
__global__ __launch_bounds__(256) void k_final(
    const float* __restrict__ psum1, const float* __restrict__ pmax1,
    const float* __restrict__ psum2, const float* __restrict__ pmax2,
    float* __restrict__ out) {
  int g = blockIdx.x, t = threadIdx.x;
  if (t < 128) {
    float a = 0.f, b = 0.f;
#pragma unroll
    for (int c = 0; c < 8; ++c) {
      a += psum1[(size_t)(g * 8 + c) * NH + t];
      b += psum2[(size_t)(g * 8 + c) * NH + t];
    }
    out[(size_t)g * 256 + t] = a / (float)KP1 + b / (float)KP2;
  } else {
    int f = t - 128;
    float a = -1e30f, b = -1e30f;
#pragma unroll
    for (int c = 0; c < 8; ++c) {
      a = fmaxf(a, pmax1[(size_t)(g * 8 + c) * NH + f]);
      b = fmaxf(b, pmax2[(size_t)(g * 8 + c) * NH + f]);
    }
    out[(size_t)g * 256 + t] = a + b;
  }
}

// ---------------------------------------------------------------------------
extern "C" void kernel_launch(void* const* d_in, const int* in_sizes, int n_in,
                              void* d_out, int out_size, void* d_ws, size_t ws_size,
                              hipStream_t stream) {
  const float* x     = (const float*)d_in[0];
  const int*   eidx  = (const int*)d_in[1];
  const int*   src   = eidx;
  const int*   dst   = eidx + EDGES;
  const float* W1rel = (const float*)d_in[3];
  const float* b1    = (const float*)d_in[4];
  const float* W1rt  = (const float*)d_in[5];
  const float* p1w   = (const float*)d_in[6];
  const float* W2rel = (const float*)d_in[7];
  const float* b2    = (const float*)d_in[8];
  const float* W2rt  = (const float*)d_in[9];
  const float* p2w   = (const float*)d_in[10];
  float* out = (float*)d_out;

  // workspace layout (floats) — h2 aliases agg2 (see k_gemm2)
  float* ws = (float*)d_ws;
  size_t off = 0;
  float* h1    = ws + off; off += (size_t)NODES * NH;
  float* agg2  = ws + off; off += (size_t)NODES * NH;
  float* h2    = agg2;
  float* agg1  = ws + off; off += (size_t)NODES * FIN;
  float* s1    = ws + off; off += NODES;
  float* s2    = ws + off; off += NODES;
  int*   kept1 = (int*)(ws + off); off += NODES;
  int*   kept2 = (int*)(ws + off); off += NODES;
  float* psum1 = ws + off; off += 512 * NH;
  float* pmax1 = ws + off; off += 512 * NH;
  float* psum2 = ws + off; off += 512 * NH;
  float* pmax2 = ws + off; off += 512 * NH;
  float* Wt2   = ws + off; off += 256 * NH;
  float* rn1   = ws + off; off += 1;
  float* rn2   = ws + off; off += 1;
  int*   cnt     = (int*)(ws + off); off += NODES;
  int*   rowptr  = (int*)(ws + off); off += NODES + 1;
  int*   cursor  = (int*)(ws + off); off += NODES;
  int*   bsum    = (int*)(ws + off); off += 256;
  int*   bbase   = (int*)(ws + off); off += 256;
  int*   col     = (int*)(ws + off); off += EDGES;

  // ---- CSR build ----
  hipMemsetAsync(cnt, 0, (size_t)NODES * sizeof(int), stream);
  k_hist<<<EDGES / 256, 256, 0, stream>>>(dst, cnt);
  k_scan_local<<<NODES / 256, 256, 0, stream>>>(cnt, rowptr, bsum);
  k_scan_base<<<1, 256, 0, stream>>>(bsum, bbase);
  k_scan_final<<<NODES / 256, 256, 0, stream>>>(rowptr, bbase, cursor);
  k_fill<<<EDGES / 256, 256, 0, stream>>>(src, dst, cursor, col);

  // ---- weight prep (independent) ----
  k_prep_wt2<<<128, 256, 0, stream>>>(W2rel, W2rt, Wt2);
  k_prep_norm<<<1, 128, 0, stream>>>(p1w, rn1);
  k_prep_norm<<<1, 128, 0, stream>>>(p2w, rn2);

  // ---- layer 1 ----
  k_gather1<<<NODES / 16, 256, 0, stream>>>(x, rowptr, col, agg1);
  k_gemm1<<<NODES / 64, 256, 0, stream>>>(x, agg1, W1rel, b1, W1rt, p1w, rn1,
                                          h1, s1);
  k_topk<<<BATCH, 512, 0, stream>>>(s1, nullptr, kept1, KP1);
  k_readout<<<BATCH * 8, 128, 0, stream>>>(h1, s1, kept1, psum1, pmax1);

  // ---- layer 2 ----
  k_gather2<<<NODES / 4, 256, 0, stream>>>(h1, s1, rowptr, col, kept1, agg2);
  k_gemm2<<<NODES / 64, 256, 0, stream>>>(agg2, h1, s1, kept1, Wt2, b2, p2w,
                                          rn2, h2, s2);
  k_topk<<<BATCH, 512, 0, stream>>>(s2, kept1, kept2, KP2);
  k_readout<<<BATCH * 8, 128, 0, stream>>>(h2, s2, kept2, psum2, pmax2);
  k_final<<<BATCH, 256, 0, stream>>>(psum1, pmax1, psum2, pmax2, out);
}

// Round 5
// 230.627 us; speedup vs baseline: 4.0383x; 1.1576x over previous
//
#include <hip/hip_runtime.h>
#include <cmath>

// Problem constants
#define BATCH   64
#define NPG     1024           // nodes per graph
#define NODES   65536          // BATCH*NPG
#define EDGES   524288
#define FIN     14
#define NH      128
#define KP1     820
#define KP2     656

// ---------------------------------------------------------------------------
// CSR build (by dst): histogram -> 2-level exclusive scan -> fill
// ---------------------------------------------------------------------------
__global__ __launch_bounds__(256) void k_hist(
    const int* __restrict__ dst, int* __restrict__ cnt) {
  int e = blockIdx.x * 256 + threadIdx.x;
  atomicAdd(&cnt[dst[e]], 1);
}

__global__ __launch_bounds__(256) void k_scan_local(
    const int* __restrict__ cnt, int* __restrict__ rowptr,
    int* __restrict__ bsum) {
  __shared__ int s[256];
  int t = threadIdx.x, b = blockIdx.x;
  int v = cnt[b * 256 + t];
  s[t] = v;
  __syncthreads();
  for (int d = 1; d < 256; d <<= 1) {
    int add = (t >= d) ? s[t - d] : 0;
    __syncthreads();
    s[t] += add;
    __syncthreads();
  }
  rowptr[b * 256 + t] = s[t] - v;      // exclusive, block-local
  if (t == 255) bsum[b] = s[255];
}

// merged base-scan + final: each block redundantly scans bsum[256] in LDS
__global__ __launch_bounds__(256) void k_scan_final(
    int* __restrict__ rowptr, const int* __restrict__ bsum,
    int* __restrict__ cursor) {
  __shared__ int s[256];
  int t = threadIdx.x, b = blockIdx.x;
  int v = bsum[t];
  s[t] = v;
  __syncthreads();
  for (int d = 1; d < 256; d <<= 1) {
    int add = (t >= d) ? s[t - d] : 0;
    __syncthreads();
    s[t] += add;
    __syncthreads();
  }
  int base = (b == 0) ? 0 : s[b - 1];    // exclusive prefix of block b
  int id = b * 256 + t;
  int v2 = rowptr[id] + base;
  rowptr[id] = v2;
  cursor[id] = v2;
  if (id == 0) rowptr[NODES] = EDGES;
}

__global__ __launch_bounds__(256) void k_fill(
    const int* __restrict__ src, const int* __restrict__ dst,
    int* __restrict__ cursor, int* __restrict__ col) {
  int e = blockIdx.x * 256 + threadIdx.x;
  int pos = atomicAdd(&cursor[dst[e]], 1);
  col[pos] = src[e];
}

// ---------------------------------------------------------------------------
// fused weight prep: Wt2 transpose-concat + both pool-weight norms
// ---------------------------------------------------------------------------
__global__ __launch_bounds__(256) void k_prep(
    const float* __restrict__ Wrel, const float* __restrict__ Wroot,
    const float* __restrict__ p1w, const float* __restrict__ p2w,
    float* __restrict__ Wt, float* __restrict__ rn1, float* __restrict__ rn2) {
  int id = blockIdx.x * 256 + threadIdx.x;
  int k = id >> 7, o = id & 127;
  Wt[id] = (k < NH) ? Wrel[o * NH + k] : Wroot[o * NH + (k - NH)];
  if (blockIdx.x == 0) {
    __shared__ float red[4];
    int t = threadIdx.x;
    const float* w = (t < 128) ? p1w : p2w;
    int f = t & 127;
    float q = w[f] * w[f];
#pragma unroll
    for (int d = 32; d; d >>= 1) q += __shfl_xor(q, d);
    if ((t & 63) == 0) red[t >> 6] = q;
    __syncthreads();
    if (t == 0)   *rn1 = rsqrtf(red[0] + red[1]);
    if (t == 128) *rn2 = rsqrtf(red[2] + red[3]);
  }
}

// ---------------------------------------------------------------------------
// conv1 aggregation via CSR gather (XCD-swizzled for per-graph L2 locality)
// ---------------------------------------------------------------------------
__global__ __launch_bounds__(256) void k_gather1(
    const float* __restrict__ x, const int* __restrict__ rowptr,
    const int* __restrict__ col, float* __restrict__ agg1) {
  int bid = blockIdx.x;                       // 4096 blocks, 512 per XCD chunk
  int swz = (bid & 7) * 512 + (bid >> 3);
  int t = threadIdx.x;
  int gi = t >> 4, l = t & 15;
  int n = swz * 16 + gi;
  int rs = rowptr[n], re = rowptr[n + 1];
  if (l < FIN) {
    float acc = 0.f;
    for (int j = rs; j < re; ++j) {
      int v = col[j];
      acc += x[(size_t)v * FIN + l];
    }
    agg1[(size_t)n * FIN + l] = acc;
  }
}

// ---------------------------------------------------------------------------
// conv1 GEMM + relu + fused pool1 score.
// Block 256 thr / 64 nodes; thread = 4 nodes x 8 outs (cols og*4+j, 64+og*4+j)
// ---------------------------------------------------------------------------
__global__ __launch_bounds__(256) void k_gemm1(
    const float* __restrict__ x, const float* __restrict__ agg1,
    const float* __restrict__ Wrel, const float* __restrict__ brel,
    const float* __restrict__ Wroot, const float* __restrict__ p1w,
    const float* __restrict__ rn1p, float* __restrict__ h1,
    float* __restrict__ s1) {
  __shared__ float As[64 * FIN];
  __shared__ float Xs[64 * FIN];
  __shared__ float Wl[2 * FIN][NH];
  int t = threadIdx.x;
  int nb = blockIdx.x * 64;
  for (int i = t; i < 64 * FIN; i += 256) {
    As[i] = agg1[(size_t)nb * FIN + i];
    Xs[i] = x[(size_t)nb * FIN + i];
  }
  for (int i = t; i < NH * FIN; i += 256) {
    int o = i / FIN, k = i - o * FIN;
    Wl[k][o]       = Wrel[i];
    Wl[k + FIN][o] = Wroot[i];
  }
  __syncthreads();
  int og = t & 15, ng = t >> 4, ra = ng * 4;
  float bb[8], pw[8];
#pragma unroll
  for (int j = 0; j < 4; ++j) {
    int c0 = og * 4 + j, c1 = 64 + og * 4 + j;
    bb[j] = brel[c0]; bb[j + 4] = brel[c1];
    pw[j] = p1w[c0];  pw[j + 4] = p1w[c1];
  }
  float acc[4][8];
#pragma unroll
  for (int i = 0; i < 4; ++i)
#pragma unroll
    for (int j = 0; j < 8; ++j) acc[i][j] = bb[j];
#pragma unroll
  for (int k = 0; k < FIN; ++k) {
    float4 w0 = *(const float4*)&Wl[k][og * 4];
    float4 w1 = *(const float4*)&Wl[k][64 + og * 4];
#pragma unroll
    for (int i = 0; i < 4; ++i) {
      float a = As[(ra + i) * FIN + k];
      acc[i][0] += a * w0.x; acc[i][1] += a * w0.y;
      acc[i][2] += a * w0.z; acc[i][3] += a * w0.w;
      acc[i][4] += a * w1.x; acc[i][5] += a * w1.y;
      acc[i][6] += a * w1.z; acc[i][7] += a * w1.w;
    }
  }
#pragma unroll
  for (int k = 0; k < FIN; ++k) {
    float4 w0 = *(const float4*)&Wl[FIN + k][og * 4];
    float4 w1 = *(const float4*)&Wl[FIN + k][64 + og * 4];
#pragma unroll
    for (int i = 0; i < 4; ++i) {
      float a = Xs[(ra + i) * FIN + k];
      acc[i][0] += a * w0.x; acc[i][1] += a * w0.y;
      acc[i][2] += a * w0.z; acc[i][3] += a * w0.w;
      acc[i][4] += a * w1.x; acc[i][5] += a * w1.y;
      acc[i][6] += a * w1.z; acc[i][7] += a * w1.w;
    }
  }
  float rnorm = *rn1p;
#pragma unroll
  for (int i = 0; i < 4; ++i) {
    int n = nb + ra + i;
    float pv = 0.f;
#pragma unroll
    for (int j = 0; j < 8; ++j) {
      float v = fmaxf(acc[i][j], 0.f);
      acc[i][j] = v;
      pv += v * pw[j];
    }
    *(float4*)(h1 + (size_t)n * NH + og * 4) =
        make_float4(acc[i][0], acc[i][1], acc[i][2], acc[i][3]);
    *(float4*)(h1 + (size_t)n * NH + 64 + og * 4) =
        make_float4(acc[i][4], acc[i][5], acc[i][6], acc[i][7]);
    pv += __shfl_xor(pv, 1);
    pv += __shfl_xor(pv, 2);
    pv += __shfl_xor(pv, 4);
    pv += __shfl_xor(pv, 8);
    if (og == 0) s1[n] = tanhf(pv * rnorm);
  }
}

// ---------------------------------------------------------------------------
// exact per-graph top-K: 512 threads, all-active bitonic over 1024 keys
// ---------------------------------------------------------------------------
__global__ __launch_bounds__(512) void k_topk(
    const float* __restrict__ score, const int* __restrict__ mask_in,
    int* __restrict__ kept, int K) {
  __shared__ unsigned long long keys[1024];
  int t = threadIdx.x, g = blockIdx.x;
  for (int i = t; i < 1024; i += 512) {
    int n = g * NPG + i;
    unsigned int inv;
    if (mask_in && !mask_in[n]) {
      inv = 0xFFFFFFFFu;
    } else {
      unsigned int u   = __float_as_uint(score[n]);
      unsigned int ord = (u & 0x80000000u) ? ~u : (u | 0x80000000u);
      inv = ~ord;
    }
    keys[i] = ((unsigned long long)inv << 32) | (unsigned int)i;
  }
  __syncthreads();
  for (int k = 2; k <= 1024; k <<= 1) {
    for (int j = k >> 1; j > 0; j >>= 1) {
      int i = ((t & ~(j - 1)) << 1) | (t & (j - 1));
      int p = i | j;
      unsigned long long a = keys[i], b = keys[p];
      bool up = ((i & k) == 0);
      if ((a > b) == up) { keys[i] = b; keys[p] = a; }
      __syncthreads();
    }
  }
  for (int i = t; i < 1024; i += 512) {
    int idx = (int)(keys[i] & 0xFFFFFFFFu);
    kept[g * NPG + idx] = (i < K) ? 1 : 0;
  }
}

// ---------------------------------------------------------------------------
// readout partials over kept nodes: v = h[n]*s[n]  (read-only)
// 1024 blocks x 256 thr; block = 64-node chunk, two rows in flight
// partial slot = blockIdx*2 + half  (2048 slots total)
// ---------------------------------------------------------------------------
__global__ __launch_bounds__(256) void k_readout(
    const float* __restrict__ h, const float* __restrict__ s,
    const int* __restrict__ kept, float* __restrict__ psum,
    float* __restrict__ pmax) {
  int g = blockIdx.x >> 4, c = blockIdx.x & 15;
  int f = threadIdx.x & 127, half = threadIdx.x >> 7;
  int nbase = g * NPG + c * 64 + half;
  float sum = 0.f, mx = -1e30f;
  for (int i = 0; i < 64; i += 2) {
    int n = nbase + i;
    if (kept[n]) {
      float v = h[(size_t)n * NH + f] * s[n];
      sum += v;
      mx = fmaxf(mx, v);
    }
  }
  int slot = blockIdx.x * 2 + half;
  psum[(size_t)slot * NH + f] = sum;
  pmax[(size_t)slot * NH + f] = mx;
}

// ---------------------------------------------------------------------------
// conv2 aggregation: one wave per kept dst row; scale s1*kept applied on the
// fly (sx never materialized). XCD-swizzled: graph-local L2 reuse of h1 rows.
// ---------------------------------------------------------------------------
__global__ __launch_bounds__(256) void k_gather2(
    const float* __restrict__ h1, const float* __restrict__ s1,
    const int* __restrict__ rowptr, const int* __restrict__ col,
    const int* __restrict__ kept1, float* __restrict__ agg2) {
  int bid = blockIdx.x;                       // 16384 blocks, 2048 per XCD
  int swz = (bid & 7) * 2048 + (bid >> 3);
  int wave = threadIdx.x >> 6, lane = threadIdx.x & 63;
  int d = swz * 4 + wave;
  if (!kept1[d]) return;                      // row never consumed downstream
  int rs = rowptr[d], re = rowptr[d + 1];
  int deg = re - rs;
  int colv = 0; float sv = 0.f;
  if (lane < deg) {
    colv = col[rs + lane];
    sv = kept1[colv] ? s1[colv] : 0.f;
  }
  int m = deg < 64 ? deg : 64;
  float ax = 0.f, ay = 0.f;
  int nfull = m & ~3;
  int j = 0;
  for (; j < nfull; j += 4) {
    int v0 = __shfl(colv, j);
    int v1 = __shfl(colv, j + 1);
    int v2 = __shfl(colv, j + 2);
    int v3 = __shfl(colv, j + 3);
    float f0 = __shfl(sv, j);
    float f1 = __shfl(sv, j + 1);
    float f2 = __shfl(sv, j + 2);
    float f3 = __shfl(sv, j + 3);
    float2 a = *(const float2*)(h1 + (size_t)v0 * NH + lane * 2);
    float2 b = *(const float2*)(h1 + (size_t)v1 * NH + lane * 2);
    float2 c = *(const float2*)(h1 + (size_t)v2 * NH + lane * 2);
    float2 e = *(const float2*)(h1 + (size_t)v3 * NH + lane * 2);
    ax += a.x * f0 + b.x * f1 + c.x * f2 + e.x * f3;
    ay += a.y * f0 + b.y * f1 + c.y * f2 + e.y * f3;
  }
  for (; j < m; ++j) {
    int v = __shfl(colv, j);
    float f = __shfl(sv, j);
    float2 a = *(const float2*)(h1 + (size_t)v * NH + lane * 2);
    ax += a.x * f; ay += a.y * f;
  }
  for (int jj = rs + 64; jj < re; ++jj) {      // deg>64 fallback (≈never)
    int v = col[jj];
    float f = kept1[v] ? s1[v] : 0.f;
    float2 a = *(const float2*)(h1 + (size_t)v * NH + lane * 2);
    ax += a.x * f; ay += a.y * f;
  }
  *(float2*)(agg2 + (size_t)d * NH + lane * 2) = make_float2(ax, ay);
}

// ---------------------------------------------------------------------------
// conv2 GEMM (K=256 = [agg2 | h1*s1*kept]) + bias + relu + fused pool2 score.
// Block = 256 thr, 128 nodes x 128 outs; thread = 8 nodes x 8 outs.
// Thread rows ng+16*i (adjacent in wave -> 4-bank spread); out cols og*4+j,
// 64+og*4+j (2-way LDS aliasing = free, proven 0-conflict in r4).
// h2 ALIASES agg2 (block reads only its own 128 rows before writing them).
// Block->row map XCD-swizzled to match k_gather2's writer map (L2 hit).
// ---------------------------------------------------------------------------
__global__ __launch_bounds__(256) void k_gemm2(
    const float* __restrict__ agg2, const float* __restrict__ h1,
    const float* __restrict__ s1, const int* __restrict__ kept1,
    const float* __restrict__ Wt, const float* __restrict__ b2,
    const float* __restrict__ p2w, const float* __restrict__ rnorm2p,
    float* __restrict__ h2, float* __restrict__ s2) {
  __shared__ float Al[128][36];         // K-chunk tile (pad: rows 4 banks apart)
  __shared__ float Wl[32 * NH];         // 16 KB
  __shared__ float rs_l[128];           // s1*kept per row
  __shared__ float ms_l[128];           // kept mask per row
  int t = threadIdx.x;
  int bid = blockIdx.x;                 // 512 blocks, 64 per XCD chunk
  int swz = (bid & 7) * 64 + (bid >> 3);
  int nb = swz * 128;
  if (t < 128) {
    int k = kept1[nb + t];
    ms_l[t] = k ? 1.f : 0.f;
    rs_l[t] = k ? s1[nb + t] : 0.f;
  }
  int og = t & 15, ng = t >> 4;
  float acc[8][8];
#pragma unroll
  for (int i = 0; i < 8; ++i)
#pragma unroll
    for (int j = 0; j < 8; ++j) acc[i][j] = 0.f;

  int r0 = t >> 2, r1 = r0 + 64;        // staging rows
  int cs = (t & 3) * 8;                 // staging col start
#pragma unroll 1
  for (int kc = 0; kc < 8; ++kc) {
    __syncthreads();
    const float* S = (kc < 4) ? agg2 : h1;
    int kb = (kc & 3) * 32;
    float4 v00 = *(const float4*)(S + (size_t)(nb + r0) * NH + kb + cs);
    float4 v01 = *(const float4*)(S + (size_t)(nb + r0) * NH + kb + cs + 4);
    float4 v10 = *(const float4*)(S + (size_t)(nb + r1) * NH + kb + cs);
    float4 v11 = *(const float4*)(S + (size_t)(nb + r1) * NH + kb + cs + 4);
    float m0 = (kc < 4) ? ms_l[r0] : rs_l[r0];
    float m1 = (kc < 4) ? ms_l[r1] : rs_l[r1];
    v00.x *= m0; v00.y *= m0; v00.z *= m0; v00.w *= m0;
    v01.x *= m0; v01.y *= m0; v01.z *= m0; v01.w *= m0;
    v10.x *= m1; v10.y *= m1; v10.z *= m1; v10.w *= m1;
    v11.x *= m1; v11.y *= m1; v11.z *= m1; v11.w *= m1;
    *(float4*)&Al[r0][cs]     = v00;
    *(float4*)&Al[r0][cs + 4] = v01;
    *(float4*)&Al[r1][cs]     = v10;
    *(float4*)&Al[r1][cs + 4] = v11;
    {
      const float4* wsrc = (const float4*)(Wt + (size_t)kc * 32 * NH);
      float4* wdst = (float4*)Wl;
      wdst[t]       = wsrc[t];
      wdst[t + 256] = wsrc[t + 256];
      wdst[t + 512] = wsrc[t + 512];
      wdst[t + 768] = wsrc[t + 768];
    }
    __syncthreads();
#pragma unroll
    for (int kk = 0; kk < 32; ++kk) {
      float4 w0 = *(const float4*)&Wl[kk * NH + og * 4];
      float4 w1 = *(const float4*)&Wl[kk * NH + 64 + og * 4];
#pragma unroll
      for (int i = 0; i < 8; ++i) {
        float a = Al[ng + 16 * i][kk];
        acc[i][0] += a * w0.x; acc[i][1] += a * w0.y;
        acc[i][2] += a * w0.z; acc[i][3] += a * w0.w;
        acc[i][4] += a * w1.x; acc[i][5] += a * w1.y;
        acc[i][6] += a * w1.z; acc[i][7] += a * w1.w;
      }
    }
  }

  float rnorm = *rnorm2p;
  float bb[8], pw[8];
#pragma unroll
  for (int j = 0; j < 4; ++j) {
    int c0 = og * 4 + j, c1 = 64 + og * 4 + j;
    bb[j] = b2[c0]; bb[j + 4] = b2[c1];
    pw[j] = p2w[c0]; pw[j + 4] = p2w[c1];
  }
#pragma unroll
  for (int i = 0; i < 8; ++i) {
    int row = ng + 16 * i;
    int n = nb + row;
    float pv = 0.f;
#pragma unroll
    for (int j = 0; j < 8; ++j) {
      float v = fmaxf(acc[i][j] + bb[j], 0.f);
      acc[i][j] = v;
      pv += v * pw[j];
    }
    if (ms_l[row] != 0.f) {              // kept2 subset of kept1 -> safe skip
      *(float4*)(h2 + (size_t)n * NH + og * 4) =
          make_float4(acc[i][0], acc[i][1], acc[i][2], acc[i][3]);
      *(float4*)(h2 + (size_t)n * NH + 64 + og * 4) =
          make_float4(acc[i][4], acc[i][5], acc[i][6], acc[i][7]);
    }
    pv += __shfl_xor(pv, 1);
    pv += __shfl_xor(pv, 2);
    pv += __shfl_xor(pv, 4);
    pv += __shfl_xor(pv, 8);
    if (og == 0) s2[n] = tanhf(pv * rnorm);
  }
}

// ---------------------------------------------------------------------------
// final combine (32 partial slots per graph)
// ---------------------------------------------------------------------------
__global__ __launch_bounds__(256) void k_final(
    const float* __restrict__ psum1, const float* __restrict__ pmax1,
    const float* __restrict__ psum2, const float* __restrict__ pmax2,
    float* __restrict__ out) {
  int g = blockIdx.x, t = threadIdx.x;
  if (t < 128) {
    float a = 0.f, b = 0.f;
#pragma unroll
    for (int c = 0; c < 32; ++c) {
      a += psum1[(size_t)(g * 32 + c) * NH + t];
      b += psum2[(size_t)(g * 32 + c) * NH + t];
    }
    out[(size_t)g * 256 + t] = a / (float)KP1 + b / (float)KP2;
  } else {
    int f = t - 128;
    float a = -1e30f, b = -1e30f;
#pragma unroll
    for (int c = 0; c < 32; ++c) {
      a = fmaxf(a, pmax1[(size_t)(g * 32 + c) * NH + f]);
      b = fmaxf(b, pmax2[(size_t)(g * 32 + c) * NH + f]);
    }
    out[(size_t)g * 256 + t] = a + b;
  }
}

// ---------------------------------------------------------------------------
extern "C" void kernel_launch(void* const* d_in, const int* in_sizes, int n_in,
                              void* d_out, int out_size, void* d_ws, size_t ws_size,
                              hipStream_t stream) {
  const float* x     = (const float*)d_in[0];
  const int*   eidx  = (const int*)d_in[1];
  const int*   src   = eidx;
  const int*   dst   = eidx + EDGES;
  const float* W1rel = (const float*)d_in[3];
  const float* b1    = (const float*)d_in[4];
  const float* W1rt  = (const float*)d_in[5];
  const float* p1w   = (const float*)d_in[6];
  const float* W2rel = (const float*)d_in[7];
  const float* b2    = (const float*)d_in[8];
  const float* W2rt  = (const float*)d_in[9];
  const float* p2w   = (const float*)d_in[10];
  float* out = (float*)d_out;

  // workspace layout (floats) — h2 aliases agg2 (see k_gemm2)
  float* ws = (float*)d_ws;
  size_t off = 0;
  float* h1    = ws + off; off += (size_t)NODES * NH;
  float* agg2  = ws + off; off += (size_t)NODES * NH;
  float* h2    = agg2;
  float* agg1  = ws + off; off += (size_t)NODES * FIN;
  float* s1    = ws + off; off += NODES;
  float* s2    = ws + off; off += NODES;
  int*   kept1 = (int*)(ws + off); off += NODES;
  int*   kept2 = (int*)(ws + off); off += NODES;
  float* psum1 = ws + off; off += 2048 * NH;
  float* pmax1 = ws + off; off += 2048 * NH;
  float* psum2 = ws + off; off += 2048 * NH;
  float* pmax2 = ws + off; off += 2048 * NH;
  float* Wt2   = ws + off; off += 256 * NH;
  float* rn1   = ws + off; off += 1;
  float* rn2   = ws + off; off += 1;
  int*   cnt     = (int*)(ws + off); off += NODES;
  int*   rowptr  = (int*)(ws + off); off += NODES + 1;
  int*   cursor  = (int*)(ws + off); off += NODES;
  int*   bsum    = (int*)(ws + off); off += 256;
  int*   col     = (int*)(ws + off); off += EDGES;

  // ---- CSR build ----
  hipMemsetAsync(cnt, 0, (size_t)NODES * sizeof(int), stream);
  k_hist<<<EDGES / 256, 256, 0, stream>>>(dst, cnt);
  k_scan_local<<<NODES / 256, 256, 0, stream>>>(cnt, rowptr, bsum);
  k_scan_final<<<NODES / 256, 256, 0, stream>>>(rowptr, bsum, cursor);
  k_fill<<<EDGES / 256, 256, 0, stream>>>(src, dst, cursor, col);

  // ---- weight prep (independent) ----
  k_prep<<<128, 256, 0, stream>>>(W2rel, W2rt, p1w, p2w, Wt2, rn1, rn2);

  // ---- layer 1 ----
  k_gather1<<<NODES / 16, 256, 0, stream>>>(x, rowptr, col, agg1);
  k_gemm1<<<NODES / 64, 256, 0, stream>>>(x, agg1, W1rel, b1, W1rt, p1w, rn1,
                                          h1, s1);
  k_topk<<<BATCH, 512, 0, stream>>>(s1, nullptr, kept1, KP1);
  k_readout<<<BATCH * 16, 256, 0, stream>>>(h1, s1, kept1, psum1, pmax1);

  // ---- layer 2 ----
  k_gather2<<<NODES / 4, 256, 0, stream>>>(h1, s1, rowptr, col, kept1, agg2);
  k_gemm2<<<NODES / 128, 256, 0, stream>>>(agg2, h1, s1, kept1, Wt2, b2, p2w,
                                           rn2, h2, s2);
  k_topk<<<BATCH, 512, 0, stream>>>(s2, kept1, kept2, KP2);
  k_readout<<<BATCH * 16, 256, 0, stream>>>(h2, s2, kept2, psum2, pmax2);
  k_final<<<BATCH, 256, 0, stream>>>(psum1, pmax1, psum2, pmax2, out);
}